// Round 7
// baseline (561.004 us; speedup 1.0000x reference)
//
#include <hip/hip_runtime.h>
#include <math.h>

#define HW 16384

typedef unsigned int uint;
typedef short bfrag __attribute__((ext_vector_type(8)));   // 8 bf16 (4 VGPRs)
typedef float f32x4 __attribute__((ext_vector_type(4)));   // 4 fp32 acc

union FragCvt { uint4 u; bfrag v; };

// round-to-nearest-even f32 -> bf16, pack two into a dword
__device__ inline uint pack2bf(float a, float b) {
  uint ua = __builtin_bit_cast(uint, a);
  uint ub = __builtin_bit_cast(uint, b);
  ua = (ua + 0x7FFFu + ((ua >> 16) & 1u)) >> 16;
  ub = (ub + 0x7FFFu + ((ub >> 16) & 1u)) & 0xFFFF0000u;
  return ua | ub;
}

// split 8 f32 into hi-bf16 frag and lo-bf16 frag (hi = RNE(x), lo = RNE(x-hi))
__device__ inline void cvt_hilo(float4 a, float4 b, bfrag& hi, bfrag& lo) {
  float v0[8] = {a.x, a.y, a.z, a.w, b.x, b.y, b.z, b.w};
  uint hv[4], lv[4];
  #pragma unroll
  for (int i = 0; i < 4; ++i) {
    float x0 = v0[2 * i], x1 = v0[2 * i + 1];
    uint h = pack2bf(x0, x1);
    float h0 = __builtin_bit_cast(float, h << 16);
    float h1 = __builtin_bit_cast(float, h & 0xFFFF0000u);
    hv[i] = h;
    lv[i] = pack2bf(x0 - h0, x1 - h1);
  }
  FragCvt ch, cl;
  ch.u = make_uint4(hv[0], hv[1], hv[2], hv[3]);
  cl.u = make_uint4(lv[0], lv[1], lv[2], lv[3]);
  hi = ch.v;
  lo = cl.v;
}

// LDS-only barrier: waits for this wave's LDS ops (lgkmcnt) but lets global
// loads (vmcnt) stay in flight across the barrier.
#define LDS_BARRIER() do { \
  asm volatile("s_waitcnt lgkmcnt(0)" ::: "memory"); \
  __builtin_amdgcn_s_barrier(); \
} while (0)

// ---------------------------------------------------------------------------
// mod[b,c] = 1 + (k_v[:, :192] @ w_kR.T) for c<192, else 1 + (k_v[:,192:] @ w_kI.T)
__global__ __launch_bounds__(256) void mod_kernel(
    const float* __restrict__ kv, const float* __restrict__ wkR,
    const float* __restrict__ wkI, float* __restrict__ mod)
{
  int b = blockIdx.x;
  int c = threadIdx.x;
  const float* kvb = kv + b * 256;
  float s = 0.f;
  if (c < 192) {
    const float* wr = wkR + c * 192;
    for (int j = 0; j < 192; ++j) s += kvb[j] * wr[j];
  } else {
    const float* wi = wkI + (c - 192) * 64;
    for (int j = 0; j < 64; ++j) s += kvb[192 + j] * wi[j];
  }
  mod[b * 256 + c] = 1.f + s;
}

// ---------------------------------------------------------------------------
// bf16-MFMA GEMM body: Y[128 x 128px tile] = W[128,K] @ (X[k,:] * mod[k])
// 256 threads = 4 waves (2x2 of 64x64), 4x4 frags of 16x16x32; f32 accum.
// X loads prefetched depth 2; LDS_BARRIER keeps them in flight across
// barriers (no vmcnt drain). W loads depth 1. mod staged once in LDS.
__device__ __forceinline__ void mgemm_body(
    const float* __restrict__ Wt, int ldW,
    const float* __restrict__ Xt,
    const float* __restrict__ modc,
    float* __restrict__ Yt,
    int K, int t, unsigned short* Al, unsigned short* Bl, float* Ml)
{
  int w = t >> 6, l = t & 63;
  int wm = (w >> 1) * 64, wn = (w & 1) * 64;
  int lm = l & 15, lk = (l >> 4) * 8;

  int am = t >> 1, ako = (t & 1) * 16;
  int bn = t & 127, bo = (t >> 7) * 8;

  Ml[t] = (modc && t < K) ? modc[t] : 1.f;

  f32x4 acc[4][4];
  #pragma unroll
  for (int fi = 0; fi < 4; ++fi)
    #pragma unroll
    for (int fj = 0; fj < 4; ++fj) acc[fi][fj] = {0.f, 0.f, 0.f, 0.f};

  float xrA[16], xrB[16];
  float4 wv0, wv1, wv2, wv3;

  auto load_x = [&](float* xr, int k0) {
    #pragma unroll
    for (int i = 0; i < 2; ++i) {
      int kb = k0 + bo + i * 16;
      #pragma unroll
      for (int r = 0; r < 8; ++r)
        xr[i * 8 + r] = Xt[(size_t)(kb + r) * HW + bn];
    }
  };
  auto load_w = [&](int k0) {
    const float* wsrc = Wt + (size_t)am * ldW + k0 + ako;
    wv0 = *(const float4*)(wsrc);
    wv1 = *(const float4*)(wsrc + 4);
    wv2 = *(const float4*)(wsrc + 8);
    wv3 = *(const float4*)(wsrc + 12);
  };
  auto pack_a = [&]() {
    uint4 aw0, aw1;
    aw0.x = pack2bf(wv0.x, wv0.y); aw0.y = pack2bf(wv0.z, wv0.w);
    aw0.z = pack2bf(wv1.x, wv1.y); aw0.w = pack2bf(wv1.z, wv1.w);
    aw1.x = pack2bf(wv2.x, wv2.y); aw1.y = pack2bf(wv2.z, wv2.w);
    aw1.z = pack2bf(wv3.x, wv3.y); aw1.w = pack2bf(wv3.z, wv3.w);
    *(uint4*)&Al[am * 40 + ako] = aw0;
    *(uint4*)&Al[am * 40 + ako + 8] = aw1;
  };
  auto pack_b = [&](const float* xr, int k0) {
    #pragma unroll
    for (int i = 0; i < 2; ++i) {
      float4 m0 = *(const float4*)&Ml[k0 + bo + i * 16];
      float4 m1 = *(const float4*)&Ml[k0 + bo + i * 16 + 4];
      uint4 bw;
      bw.x = pack2bf(xr[i * 8 + 0] * m0.x, xr[i * 8 + 1] * m0.y);
      bw.y = pack2bf(xr[i * 8 + 2] * m0.z, xr[i * 8 + 3] * m0.w);
      bw.z = pack2bf(xr[i * 8 + 4] * m1.x, xr[i * 8 + 5] * m1.y);
      bw.w = pack2bf(xr[i * 8 + 6] * m1.z, xr[i * 8 + 7] * m1.w);
      *(uint4*)&Bl[bn * 40 + bo + i * 16] = bw;
    }
  };
  auto mfma_step = [&]() {
    bfrag af[4], bfr[4];
    #pragma unroll
    for (int fj = 0; fj < 4; ++fj) {
      FragCvt cv;
      cv.u = *(const uint4*)&Al[(wm + fj * 16 + lm) * 40 + lk];
      af[fj] = cv.v;
    }
    #pragma unroll
    for (int fi = 0; fi < 4; ++fi) {
      FragCvt cv;
      cv.u = *(const uint4*)&Bl[(wn + fi * 16 + lm) * 40 + lk];
      bfr[fi] = cv.v;
    }
    #pragma unroll
    for (int fi = 0; fi < 4; ++fi)
      #pragma unroll
      for (int fj = 0; fj < 4; ++fj)
        acc[fi][fj] = __builtin_amdgcn_mfma_f32_16x16x32_bf16(
            bfr[fi], af[fj], acc[fi][fj], 0, 0, 0);
  };

  load_x(xrA, 0);
  load_x(xrB, 32);
  load_w(0);

  for (int k0 = 0; k0 < K; k0 += 64) {
    LDS_BARRIER();
    pack_a();
    if (k0 + 32 < K) load_w(k0 + 32);
    pack_b(xrA, k0);
    if (k0 + 64 < K) load_x(xrA, k0 + 64);
    LDS_BARRIER();
    mfma_step();

    LDS_BARRIER();
    pack_a();
    if (k0 + 64 < K) load_w(k0 + 64);
    pack_b(xrB, k0 + 32);
    if (k0 + 96 < K) load_x(xrB, k0 + 96);
    LDS_BARRIER();
    mfma_step();
  }

  int ph = (l >> 4) * 4;
  #pragma unroll
  for (int fi = 0; fi < 4; ++fi)
    #pragma unroll
    for (int fj = 0; fj < 4; ++fj)
      *(f32x4*)&Yt[(size_t)(wm + fj * 16 + lm) * HW + wn + fi * 16 + ph] =
          acc[fi][fj];
}

__global__ __launch_bounds__(256, 2) void mgemm(
    const float* __restrict__ W, int ldW, size_t Wbstride,
    const float* __restrict__ X, int c0, size_t Xbstride,
    const float* __restrict__ mod,
    float* __restrict__ Y, size_t Ybstride, int K)
{
  __shared__ unsigned short Al[128 * 40];
  __shared__ unsigned short Bl[128 * 40];
  __shared__ float Ml[256];
  int b = blockIdx.z, mt = blockIdx.y, nt = blockIdx.x;
  mgemm_body(W + (size_t)b * Wbstride + (size_t)mt * 128 * ldW, ldW,
             X + (size_t)b * Xbstride + (size_t)c0 * HW + nt * 128,
             mod ? mod + b * 256 + c0 : (const float*)nullptr,
             Y + (size_t)b * Ybstride + (size_t)mt * 128 * HW + nt * 128,
             K, threadIdx.x, Al, Bl, Ml);
}

// merged q (mt 0-1, K=192, c0=0) + k (mt 2-3, K=64, c0=192) projections
__global__ __launch_bounds__(256, 2) void mgemm_qk(
    const float* __restrict__ wqR, const float* __restrict__ wkvI,
    const float* __restrict__ X, const float* __restrict__ mod,
    float* __restrict__ Yq, float* __restrict__ Yk)
{
  __shared__ unsigned short Al[128 * 40];
  __shared__ unsigned short Bl[128 * 40];
  __shared__ float Ml[256];
  int b = blockIdx.z, mt = blockIdx.y, nt = blockIdx.x;
  if (mt < 2) {
    mgemm_body(wqR + (size_t)mt * 128 * 192, 192,
               X + (size_t)b * 4194304 + nt * 128,
               mod + b * 256,
               Yq + (size_t)b * 4194304 + (size_t)mt * 128 * HW + nt * 128,
               192, threadIdx.x, Al, Bl, Ml);
  } else {
    int m2 = mt - 2;
    mgemm_body(wkvI + (size_t)m2 * 128 * 64, 64,
               X + (size_t)b * 4194304 + (size_t)192 * HW + nt * 128,
               mod + b * 256 + 192,
               Yk + (size_t)b * 4194304 + (size_t)m2 * 128 * HW + nt * 128,
               64, threadIdx.x, Al, Bl, Ml);
  }
}

// ---------------------------------------------------------------------------
// depthwise 3x3, SAME zero pad. One block per (channel, batch). (v path only)
__global__ __launch_bounds__(256) void dwconv_kernel(
    const float* __restrict__ in, size_t in_bstride,
    const float* __restrict__ wdw,
    float* __restrict__ out, size_t out_bstride,
    float* __restrict__ ssq)
{
  int c = blockIdx.x;
  int b = blockIdx.y;
  int t = threadIdx.x;
  int r = t >> 5;
  int xq = t & 31;

  const float4* ip4 = (const float4*)(in + (size_t)b * in_bstride + ((size_t)c << 14));
  float4* op4 = (float4*)(out + (size_t)b * out_bstride + ((size_t)c << 14));
  const float* wp = wdw + c * 9;
  float w0 = wp[0], w1 = wp[1], w2 = wp[2], w3 = wp[3], w4 = wp[4],
        w5 = wp[5], w6 = wp[6], w7 = wp[7], w8 = wp[8];

  const float4 z4 = make_float4(0.f, 0.f, 0.f, 0.f);
  int y0 = r << 4;

  float4 a = (y0 > 0) ? ip4[((y0 - 1) << 5) + xq] : z4;
  float4 bb = ip4[(y0 << 5) + xq];

  float aL = __shfl_up(a.w, 1);  if (xq == 0)  aL = 0.f;
  float aR = __shfl_down(a.x, 1); if (xq == 31) aR = 0.f;
  float bL = __shfl_up(bb.w, 1); if (xq == 0)  bL = 0.f;
  float bR = __shfl_down(bb.x, 1); if (xq == 31) bR = 0.f;

  float ss = 0.f;
  #pragma unroll
  for (int i = 0; i < 16; ++i) {
    int y = y0 + i;
    int yc = (y + 1 < 128) ? (y + 1) : 127;
    float4 cc = ip4[(yc << 5) + xq];
    if (y + 1 >= 128) { cc.x = 0.f; cc.y = 0.f; cc.z = 0.f; cc.w = 0.f; }
    float cL = __shfl_up(cc.w, 1);  if (xq == 0)  cL = 0.f;
    float cR = __shfl_down(cc.x, 1); if (xq == 31) cR = 0.f;

    float4 o;
    o.x = w0 * aL  + w1 * a.x + w2 * a.y +
          w3 * bL  + w4 * bb.x + w5 * bb.y +
          w6 * cL  + w7 * cc.x + w8 * cc.y;
    o.y = w0 * a.x + w1 * a.y + w2 * a.z +
          w3 * bb.x + w4 * bb.y + w5 * bb.z +
          w6 * cc.x + w7 * cc.y + w8 * cc.z;
    o.z = w0 * a.y + w1 * a.z + w2 * a.w +
          w3 * bb.y + w4 * bb.z + w5 * bb.w +
          w6 * cc.y + w7 * cc.z + w8 * cc.w;
    o.w = w0 * a.z + w1 * a.w + w2 * aR +
          w3 * bb.z + w4 * bb.w + w5 * bR +
          w6 * cc.z + w7 * cc.w + w8 * cR;

    op4[(y << 5) + xq] = o;
    ss += o.x * o.x + o.y * o.y + o.z * o.z + o.w * o.w;

    a = bb; aL = bL; aR = bR;
    bb = cc; bL = cL; bR = cR;
  }

  if (ssq) {
    #pragma unroll
    for (int off = 32; off > 0; off >>= 1) ss += __shfl_down(ss, off);
    __shared__ float red[4];
    if ((t & 63) == 0) red[t >> 6] = ss;
    __syncthreads();
    if (t == 0) ssq[b * 256 + c] = red[0] + red[1] + red[2] + red[3];
  }
}

// ---------------------------------------------------------------------------
// FUSED dwconv + Gram:
//   S[b,h,c,d] += sum_px dw(q_pre)[c,px] * dw(k_pre)[d,px]
//   ssq[b,c]  += dw(q_pre)[c,px]^2 ; ssk likewise   (atomic accum, pre-zeroed)
// grid (32, 8, 4) = (chunk of 4 rows, head, batch); 256 thr = 4 waves.
// Wave w handles image row Y = chunk*4 + w. Lane: lm = l&15 -> channels
// (h*32+lm, +16); lk8 = (l>>4)*8 -> x-offset; s=0..3 -> x0 = lk8 + 32s.
// Conv in f32 (same tap order as dwconv_kernel), then hi/lo bf16 MFMA.
__global__ __launch_bounds__(256, 3) void gram_fused(
    const float* __restrict__ qpre, const float* __restrict__ kpre,
    const float* __restrict__ wqdw, const float* __restrict__ wkdw,
    float* __restrict__ S, float* __restrict__ ssq, float* __restrict__ ssk)
{
  int chunk = blockIdx.x, h = blockIdx.y, b = blockIdx.z;
  int t = threadIdx.x;
  int w = t >> 6, l = t & 63;
  int lm = l & 15, lk8 = (l >> 4) * 8;
  int Y = chunk * 4 + w;

  int c0 = h * 32 + lm, c1 = c0 + 16;
  const float* q0p = qpre + (((size_t)b * 256 + c0) << 14);
  const float* q1p = qpre + (((size_t)b * 256 + c1) << 14);
  const float* k0p = kpre + (((size_t)b * 256 + c0) << 14);
  const float* k1p = kpre + (((size_t)b * 256 + c1) << 14);

  float wq0[9], wq1[9], wk0[9], wk1[9];
  #pragma unroll
  for (int j = 0; j < 9; ++j) {
    wq0[j] = wqdw[c0 * 9 + j]; wq1[j] = wqdw[c1 * 9 + j];
    wk0[j] = wkdw[c0 * 9 + j]; wk1[j] = wkdw[c1 * 9 + j];
  }

  bool ym = Y > 0, yp = Y < 127;
  int r0 = Y << 7;
  int rm = ym ? r0 - 128 : r0;   // clamped; zeroed below when invalid
  int rp = yp ? r0 + 128 : r0;

  f32x4 acc[2][2], accl[2][2];
  #pragma unroll
  for (int mi = 0; mi < 2; ++mi)
    #pragma unroll
    for (int nj = 0; nj < 2; ++nj) {
      acc[mi][nj] = {0.f, 0.f, 0.f, 0.f};
      accl[mi][nj] = {0.f, 0.f, 0.f, 0.f};
    }
  float nq0 = 0.f, nq1 = 0.f, nk0 = 0.f, nk1 = 0.f;

  // conv of 8 outputs at (row Y, x0..x0+7) of one channel plane
  auto conv8 = [&](const float* base, const float* wt, int x0, float* o) {
    float A[3][10];
    int rows[3] = {rm, r0, rp};
    #pragma unroll
    for (int dy = 0; dy < 3; ++dy) {
      const float* p = base + rows[dy] + x0;
      float4 m0 = *(const float4*)p;
      float4 m1 = *(const float4*)(p + 4);
      int lo = (x0 > 0) ? -1 : 0;          // in-bounds clamped offsets
      int ro = (x0 + 8 < 128) ? 8 : 7;
      float lv = p[lo];
      float rv = p[ro];
      if (x0 == 0) lv = 0.f;
      if (x0 + 8 >= 128) rv = 0.f;
      bool valid = (dy == 0) ? ym : ((dy == 2) ? yp : true);
      if (!valid) {
        m0 = make_float4(0.f, 0.f, 0.f, 0.f);
        m1 = make_float4(0.f, 0.f, 0.f, 0.f);
        lv = 0.f; rv = 0.f;
      }
      A[dy][0] = lv;
      A[dy][1] = m0.x; A[dy][2] = m0.y; A[dy][3] = m0.z; A[dy][4] = m0.w;
      A[dy][5] = m1.x; A[dy][6] = m1.y; A[dy][7] = m1.z; A[dy][8] = m1.w;
      A[dy][9] = rv;
    }
    #pragma unroll
    for (int j = 0; j < 8; ++j)
      o[j] = wt[0] * A[0][j] + wt[1] * A[0][j + 1] + wt[2] * A[0][j + 2] +
             wt[3] * A[1][j] + wt[4] * A[1][j + 1] + wt[5] * A[1][j + 2] +
             wt[6] * A[2][j] + wt[7] * A[2][j + 1] + wt[8] * A[2][j + 2];
  };

  for (int s = 0; s < 4; ++s) {
    int x0 = lk8 + 32 * s;
    float oq0[8], oq1[8], ok0[8], ok1[8];
    conv8(q0p, wq0, x0, oq0);
    conv8(q1p, wq1, x0, oq1);
    conv8(k0p, wk0, x0, ok0);
    conv8(k1p, wk1, x0, ok1);
    #pragma unroll
    for (int j = 0; j < 8; ++j) {
      nq0 += oq0[j] * oq0[j]; nq1 += oq1[j] * oq1[j];
      nk0 += ok0[j] * ok0[j]; nk1 += ok1[j] * ok1[j];
    }
    bfrag qhF[2], qlF[2], khF[2], klF[2];
    cvt_hilo(make_float4(oq0[0], oq0[1], oq0[2], oq0[3]),
             make_float4(oq0[4], oq0[5], oq0[6], oq0[7]), qhF[0], qlF[0]);
    cvt_hilo(make_float4(oq1[0], oq1[1], oq1[2], oq1[3]),
             make_float4(oq1[4], oq1[5], oq1[6], oq1[7]), qhF[1], qlF[1]);
    cvt_hilo(make_float4(ok0[0], ok0[1], ok0[2], ok0[3]),
             make_float4(ok0[4], ok0[5], ok0[6], ok0[7]), khF[0], klF[0]);
    cvt_hilo(make_float4(ok1[0], ok1[1], ok1[2], ok1[3]),
             make_float4(ok1[4], ok1[5], ok1[6], ok1[7]), khF[1], klF[1]);

    #pragma unroll
    for (int mi = 0; mi < 2; ++mi)
      #pragma unroll
      for (int nj = 0; nj < 2; ++nj) {
        acc[mi][nj] = __builtin_amdgcn_mfma_f32_16x16x32_bf16(
            qhF[mi], khF[nj], acc[mi][nj], 0, 0, 0);
        accl[mi][nj] = __builtin_amdgcn_mfma_f32_16x16x32_bf16(
            qhF[mi], klF[nj], accl[mi][nj], 0, 0, 0);
        accl[mi][nj] = __builtin_amdgcn_mfma_f32_16x16x32_bf16(
            qlF[mi], khF[nj], accl[mi][nj], 0, 0, 0);
      }
  }

  // norms: butterfly over the 4 lanes sharing a channel, one atomic each
  nq0 += __shfl_xor(nq0, 16); nq0 += __shfl_xor(nq0, 32);
  nq1 += __shfl_xor(nq1, 16); nq1 += __shfl_xor(nq1, 32);
  nk0 += __shfl_xor(nk0, 16); nk0 += __shfl_xor(nk0, 32);
  nk1 += __shfl_xor(nk1, 16); nk1 += __shfl_xor(nk1, 32);
  if (l < 16) {
    atomicAdd(&ssq[b * 256 + c0], nq0);
    atomicAdd(&ssq[b * 256 + c1], nq1);
    atomicAdd(&ssk[b * 256 + c0], nk0);
    atomicAdd(&ssk[b * 256 + c1], nk1);
  }

  // reduce the 4 waves' partial 32x32 tiles through LDS, then one
  // atomicAdd per element per block.
  __shared__ float red[4][1024];
  int orow = (l >> 4) * 4;
  #pragma unroll
  for (int mi = 0; mi < 2; ++mi)
    #pragma unroll
    for (int nj = 0; nj < 2; ++nj)
      #pragma unroll
      for (int r = 0; r < 4; ++r)
        red[w][(mi * 16 + orow + r) * 32 + nj * 16 + lm] =
            acc[mi][nj][r] + accl[mi][nj][r];
  __syncthreads();
  float* Sp = S + (((size_t)b * 8 + h) << 10);
  for (int idx = t; idx < 1024; idx += 256)
    atomicAdd(&Sp[idx], red[0][idx] + red[1][idx] + red[2][idx] + red[3][idx]);
}

// ---------------------------------------------------------------------------
// in-place: S <- softmax_d( S / (max(|q|,eps)*max(|k|,eps)) * temp[h] )
__global__ __launch_bounds__(64) void softmax_kernel(
    float* __restrict__ S, const float* __restrict__ ssq,
    const float* __restrict__ ssk, const float* __restrict__ temp)
{
  int bh = blockIdx.x;
  int b = bh >> 3, h = bh & 7;
  int c = threadIdx.x;
  if (c >= 32) return;
  float* row = S + ((size_t)bh << 10) + c * 32;
  float invq = 1.f / fmaxf(sqrtf(ssq[b * 256 + h * 32 + c]), 1e-12f);
  float T = temp[h];
  float lg[32];
  float mx = -1e30f;
  for (int d = 0; d < 32; ++d) {
    float invk = 1.f / fmaxf(sqrtf(ssk[b * 256 + h * 32 + d]), 1e-12f);
    float v = row[d] * invq * invk * T;
    lg[d] = v;
    mx = fmaxf(mx, v);
  }
  float sum = 0.f;
  for (int d = 0; d < 32; ++d) { float e = expf(lg[d] - mx); lg[d] = e; sum += e; }
  float inv = 1.f / sum;
  for (int d = 0; d < 32; ++d) row[d] = lg[d] * inv;
}

// ---------------------------------------------------------------------------
// M[b][o][h*32+d] = sum_c w_proj[o][h*32+c] * attn[b,h,c,d]
__global__ __launch_bounds__(256) void mbuild_kernel(
    const float* __restrict__ attn, const float* __restrict__ wproj,
    float* __restrict__ M)
{
  int o = blockIdx.x, b = blockIdx.y;
  int col = threadIdx.x;
  int h = col >> 5, d = col & 31;
  const float* a = attn + (((size_t)b * 8 + h) << 10);
  const float* wp = wproj + o * 256 + h * 32;
  float s = 0.f;
  #pragma unroll
  for (int cc = 0; cc < 32; ++cc) s += wp[cc] * a[cc * 32 + d];
  M[((size_t)b * 256 + o) * 256 + col] = s;
}

// ---------------------------------------------------------------------------
extern "C" void kernel_launch(void* const* d_in, const int* in_sizes, int n_in,
                              void* d_out, int out_size, void* d_ws, size_t ws_size,
                              hipStream_t stream)
{
  const float* x      = (const float*)d_in[0];
  const float* k_v    = (const float*)d_in[1];
  const float* temp   = (const float*)d_in[2];
  const float* w_kR   = (const float*)d_in[3];
  const float* w_kI   = (const float*)d_in[4];
  const float* w_qR   = (const float*)d_in[5];
  const float* w_qdw  = (const float*)d_in[6];
  const float* w_kvI  = (const float*)d_in[7];
  const float* w_kvdw = (const float*)d_in[8];
  const float* w_proj = (const float*)d_in[9];
  float* out = (float*)d_out;

  float* ws   = (float*)d_ws;
  float* bufA = ws;                 // 64 MB
  float* bufB = ws + 16777216;      // 64 MB
  float* bufC = ws + 33554432;      // 64 MB
  float* sm   = ws + 50331648;      // small region at 192 MB
  float* mod  = sm;                 // 1024
  float* ssq  = sm + 1024;          // 1024 (q norms^2, atomic accum)
  float* ssk  = sm + 2048;          // 1024 (k norms^2, atomic accum)
  float* S    = sm + 3072;          // 32768 (Gram -> attn in place)
  float* M    = sm + 3072 + 32768;  // 262144 (fused attn+proj matrix)

  // zero ssq, ssk, S (contiguous)
  hipMemsetAsync(ssq, 0, (size_t)(1024 + 1024 + 32768) * sizeof(float), stream);

  mod_kernel<<<dim3(4), dim3(256), 0, stream>>>(k_v, w_kR, w_kI, mod);

  // q_pre -> bufA ; k_pre -> bufB  (merged launch, 2048 blocks)
  mgemm_qk<<<dim3(128, 4, 4), dim3(256), 0, stream>>>(
      w_qR, w_kvI, x, mod, bufA, bufB);

  // fused dwconv(q,k) + Gram + norms
  gram_fused<<<dim3(32, 8, 4), dim3(256), 0, stream>>>(
      bufA, bufB, w_qdw, w_kvdw, S, ssq, ssk);

  // v_pre -> bufC
  mgemm<<<dim3(128, 2, 4), dim3(256), 0, stream>>>(
      w_kvI + 256 * 64, 64, 0, x, 192, 4194304, mod, bufC, 4194304, 64);

  // attn (in place on S), then M = w_proj @ blockdiag(attn)
  softmax_kernel<<<dim3(32), dim3(64), 0, stream>>>(S, ssq, ssk, temp);
  mbuild_kernel<<<dim3(256, 4), dim3(256), 0, stream>>>(S, w_proj, M);

  // vdw -> bufA (q_pre dead after gram_fused)
  dwconv_kernel<<<dim3(256, 4), dim3(256), 0, stream>>>(
      bufC, 4194304, w_kvdw + 256 * 9, bufA, 4194304, (float*)nullptr);

  // out = M[b] @ vdw[b]
  mgemm<<<dim3(128, 2, 4), dim3(256), 0, stream>>>(
      M, 256, 65536, bufA, 0, 4194304, (const float*)nullptr, out, 4194304, 256);
}

// Round 8
// 319.957 us; speedup vs baseline: 1.7534x; 1.7534x over previous
//
#include <hip/hip_runtime.h>
#include <math.h>

#define HW 16384

typedef unsigned int uint;
typedef short bfrag __attribute__((ext_vector_type(8)));   // 8 bf16 (4 VGPRs)
typedef float f32x4 __attribute__((ext_vector_type(4)));   // 4 fp32 acc

union FragCvt { uint4 u; bfrag v; };

// round-to-nearest-even f32 -> bf16, pack two into a dword
__device__ inline uint pack2bf(float a, float b) {
  uint ua = __builtin_bit_cast(uint, a);
  uint ub = __builtin_bit_cast(uint, b);
  ua = (ua + 0x7FFFu + ((ua >> 16) & 1u)) >> 16;
  ub = (ub + 0x7FFFu + ((ub >> 16) & 1u)) & 0xFFFF0000u;
  return ua | ub;
}

// split 8 f32 into hi-bf16 frag and lo-bf16 frag (hi = RNE(x), lo = RNE(x-hi))
__device__ inline void cvt_hilo(float4 a, float4 b, bfrag& hi, bfrag& lo) {
  float v0[8] = {a.x, a.y, a.z, a.w, b.x, b.y, b.z, b.w};
  uint hv[4], lv[4];
  #pragma unroll
  for (int i = 0; i < 4; ++i) {
    float x0 = v0[2 * i], x1 = v0[2 * i + 1];
    uint h = pack2bf(x0, x1);
    float h0 = __builtin_bit_cast(float, h << 16);
    float h1 = __builtin_bit_cast(float, h & 0xFFFF0000u);
    hv[i] = h;
    lv[i] = pack2bf(x0 - h0, x1 - h1);
  }
  FragCvt ch, cl;
  ch.u = make_uint4(hv[0], hv[1], hv[2], hv[3]);
  cl.u = make_uint4(lv[0], lv[1], lv[2], lv[3]);
  hi = ch.v;
  lo = cl.v;
}

// LDS-only barrier: waits for this wave's LDS ops (lgkmcnt) but lets global
// loads (vmcnt) stay in flight across the barrier.
#define LDS_BARRIER() do { \
  asm volatile("s_waitcnt lgkmcnt(0)" ::: "memory"); \
  __builtin_amdgcn_s_barrier(); \
} while (0)

// ---------------------------------------------------------------------------
// mod[b,c] = 1 + (k_v @ w.T); also zeroes S (32 float4 per thread) so the
// separate memset dispatch is not needed (gram's atomicAdds come later).
__global__ __launch_bounds__(256) void mod_kernel(
    const float* __restrict__ kv, const float* __restrict__ wkR,
    const float* __restrict__ wkI, float* __restrict__ mod,
    float* __restrict__ S)
{
  int b = blockIdx.x;
  int c = threadIdx.x;
  // zero S: thread (b,c) zeros 32 floats
  float4 z4 = make_float4(0.f, 0.f, 0.f, 0.f);
  float4* sp = (float4*)(S + (((size_t)b * 256 + c) << 5));
  #pragma unroll
  for (int i = 0; i < 8; ++i) sp[i] = z4;

  const float* kvb = kv + b * 256;
  float s = 0.f;
  if (c < 192) {
    const float* wr = wkR + c * 192;
    for (int j = 0; j < 192; ++j) s += kvb[j] * wr[j];
  } else {
    const float* wi = wkI + (c - 192) * 64;
    for (int j = 0; j < 64; ++j) s += kvb[192 + j] * wi[j];
  }
  mod[b * 256 + c] = 1.f + s;
}

// ---------------------------------------------------------------------------
// bf16-MFMA GEMM body: Y[128 x 128px tile] = W[128,K] @ (X[k,:] * mod[k])
// 256 threads = 4 waves (2x2 of 64x64), 4x4 frags of 16x16x32; f32 accum.
// X loads prefetched depth 2; LDS_BARRIER keeps them in flight across
// barriers (no vmcnt drain). W loads depth 1. mod staged once in LDS.
__device__ __forceinline__ void mgemm_body(
    const float* __restrict__ Wt, int ldW,
    const float* __restrict__ Xt,
    const float* __restrict__ modc,
    float* __restrict__ Yt,
    int K, int t, unsigned short* Al, unsigned short* Bl, float* Ml)
{
  int w = t >> 6, l = t & 63;
  int wm = (w >> 1) * 64, wn = (w & 1) * 64;
  int lm = l & 15, lk = (l >> 4) * 8;

  int am = t >> 1, ako = (t & 1) * 16;
  int bn = t & 127, bo = (t >> 7) * 8;

  Ml[t] = (modc && t < K) ? modc[t] : 1.f;

  f32x4 acc[4][4];
  #pragma unroll
  for (int fi = 0; fi < 4; ++fi)
    #pragma unroll
    for (int fj = 0; fj < 4; ++fj) acc[fi][fj] = {0.f, 0.f, 0.f, 0.f};

  float xrA[16], xrB[16];
  float4 wv0, wv1, wv2, wv3;

  auto load_x = [&](float* xr, int k0) {
    #pragma unroll
    for (int i = 0; i < 2; ++i) {
      int kb = k0 + bo + i * 16;
      #pragma unroll
      for (int r = 0; r < 8; ++r)
        xr[i * 8 + r] = Xt[(size_t)(kb + r) * HW + bn];
    }
  };
  auto load_w = [&](int k0) {
    const float* wsrc = Wt + (size_t)am * ldW + k0 + ako;
    wv0 = *(const float4*)(wsrc);
    wv1 = *(const float4*)(wsrc + 4);
    wv2 = *(const float4*)(wsrc + 8);
    wv3 = *(const float4*)(wsrc + 12);
  };
  auto pack_a = [&]() {
    uint4 aw0, aw1;
    aw0.x = pack2bf(wv0.x, wv0.y); aw0.y = pack2bf(wv0.z, wv0.w);
    aw0.z = pack2bf(wv1.x, wv1.y); aw0.w = pack2bf(wv1.z, wv1.w);
    aw1.x = pack2bf(wv2.x, wv2.y); aw1.y = pack2bf(wv2.z, wv2.w);
    aw1.z = pack2bf(wv3.x, wv3.y); aw1.w = pack2bf(wv3.z, wv3.w);
    *(uint4*)&Al[am * 40 + ako] = aw0;
    *(uint4*)&Al[am * 40 + ako + 8] = aw1;
  };
  auto pack_b = [&](const float* xr, int k0) {
    #pragma unroll
    for (int i = 0; i < 2; ++i) {
      float4 m0 = *(const float4*)&Ml[k0 + bo + i * 16];
      float4 m1 = *(const float4*)&Ml[k0 + bo + i * 16 + 4];
      uint4 bw;
      bw.x = pack2bf(xr[i * 8 + 0] * m0.x, xr[i * 8 + 1] * m0.y);
      bw.y = pack2bf(xr[i * 8 + 2] * m0.z, xr[i * 8 + 3] * m0.w);
      bw.z = pack2bf(xr[i * 8 + 4] * m1.x, xr[i * 8 + 5] * m1.y);
      bw.w = pack2bf(xr[i * 8 + 6] * m1.z, xr[i * 8 + 7] * m1.w);
      *(uint4*)&Bl[bn * 40 + bo + i * 16] = bw;
    }
  };
  auto mfma_step = [&]() {
    bfrag af[4], bfr[4];
    #pragma unroll
    for (int fj = 0; fj < 4; ++fj) {
      FragCvt cv;
      cv.u = *(const uint4*)&Al[(wm + fj * 16 + lm) * 40 + lk];
      af[fj] = cv.v;
    }
    #pragma unroll
    for (int fi = 0; fi < 4; ++fi) {
      FragCvt cv;
      cv.u = *(const uint4*)&Bl[(wn + fi * 16 + lm) * 40 + lk];
      bfr[fi] = cv.v;
    }
    #pragma unroll
    for (int fi = 0; fi < 4; ++fi)
      #pragma unroll
      for (int fj = 0; fj < 4; ++fj)
        acc[fi][fj] = __builtin_amdgcn_mfma_f32_16x16x32_bf16(
            bfr[fi], af[fj], acc[fi][fj], 0, 0, 0);
  };

  load_x(xrA, 0);
  load_x(xrB, 32);
  load_w(0);

  for (int k0 = 0; k0 < K; k0 += 64) {
    LDS_BARRIER();
    pack_a();
    if (k0 + 32 < K) load_w(k0 + 32);
    pack_b(xrA, k0);
    if (k0 + 64 < K) load_x(xrA, k0 + 64);
    LDS_BARRIER();
    mfma_step();

    LDS_BARRIER();
    pack_a();
    if (k0 + 64 < K) load_w(k0 + 64);
    pack_b(xrB, k0 + 32);
    if (k0 + 96 < K) load_x(xrB, k0 + 96);
    LDS_BARRIER();
    mfma_step();
  }

  int ph = (l >> 4) * 4;
  #pragma unroll
  for (int fi = 0; fi < 4; ++fi)
    #pragma unroll
    for (int fj = 0; fj < 4; ++fj)
      *(f32x4*)&Yt[(size_t)(wm + fj * 16 + lm) * HW + wn + fi * 16 + ph] =
          acc[fi][fj];
}

__global__ __launch_bounds__(256, 2) void mgemm(
    const float* __restrict__ W, int ldW, size_t Wbstride,
    const float* __restrict__ X, int c0, size_t Xbstride,
    const float* __restrict__ mod,
    float* __restrict__ Y, size_t Ybstride, int K)
{
  __shared__ unsigned short Al[128 * 40];
  __shared__ unsigned short Bl[128 * 40];
  __shared__ float Ml[256];
  int b = blockIdx.z, mt = blockIdx.y, nt = blockIdx.x;
  mgemm_body(W + (size_t)b * Wbstride + (size_t)mt * 128 * ldW, ldW,
             X + (size_t)b * Xbstride + (size_t)c0 * HW + nt * 128,
             mod ? mod + b * 256 + c0 : (const float*)nullptr,
             Y + (size_t)b * Ybstride + (size_t)mt * 128 * HW + nt * 128,
             K, threadIdx.x, Al, Bl, Ml);
}

// merged q (mt 0-1, K=192, c0=0) + k (mt 2-3, K=64, c0=192) projections
__global__ __launch_bounds__(256, 2) void mgemm_qk(
    const float* __restrict__ wqR, const float* __restrict__ wkvI,
    const float* __restrict__ X, const float* __restrict__ mod,
    float* __restrict__ Yq, float* __restrict__ Yk)
{
  __shared__ unsigned short Al[128 * 40];
  __shared__ unsigned short Bl[128 * 40];
  __shared__ float Ml[256];
  int b = blockIdx.z, mt = blockIdx.y, nt = blockIdx.x;
  if (mt < 2) {
    mgemm_body(wqR + (size_t)mt * 128 * 192, 192,
               X + (size_t)b * 4194304 + nt * 128,
               mod + b * 256,
               Yq + (size_t)b * 4194304 + (size_t)mt * 128 * HW + nt * 128,
               192, threadIdx.x, Al, Bl, Ml);
  } else {
    int m2 = mt - 2;
    mgemm_body(wkvI + (size_t)m2 * 128 * 64, 64,
               X + (size_t)b * 4194304 + (size_t)192 * HW + nt * 128,
               mod + b * 256 + 192,
               Yk + (size_t)b * 4194304 + (size_t)m2 * 128 * HW + nt * 128,
               64, threadIdx.x, Al, Bl, Ml);
  }
}

// ---------------------------------------------------------------------------
// depthwise 3x3, SAME zero pad. One block per (channel, batch).
__global__ __launch_bounds__(256) void dwconv_kernel(
    const float* __restrict__ in, size_t in_bstride,
    const float* __restrict__ wdw,
    float* __restrict__ out, size_t out_bstride,
    float* __restrict__ ssq)
{
  int c = blockIdx.x;
  int b = blockIdx.y;
  int t = threadIdx.x;
  int r = t >> 5;
  int xq = t & 31;

  const float4* ip4 = (const float4*)(in + (size_t)b * in_bstride + ((size_t)c << 14));
  float4* op4 = (float4*)(out + (size_t)b * out_bstride + ((size_t)c << 14));
  const float* wp = wdw + c * 9;
  float w0 = wp[0], w1 = wp[1], w2 = wp[2], w3 = wp[3], w4 = wp[4],
        w5 = wp[5], w6 = wp[6], w7 = wp[7], w8 = wp[8];

  const float4 z4 = make_float4(0.f, 0.f, 0.f, 0.f);
  int y0 = r << 4;

  float4 a = (y0 > 0) ? ip4[((y0 - 1) << 5) + xq] : z4;
  float4 bb = ip4[(y0 << 5) + xq];

  float aL = __shfl_up(a.w, 1);  if (xq == 0)  aL = 0.f;
  float aR = __shfl_down(a.x, 1); if (xq == 31) aR = 0.f;
  float bL = __shfl_up(bb.w, 1); if (xq == 0)  bL = 0.f;
  float bR = __shfl_down(bb.x, 1); if (xq == 31) bR = 0.f;

  float ss = 0.f;
  #pragma unroll
  for (int i = 0; i < 16; ++i) {
    int y = y0 + i;
    int yc = (y + 1 < 128) ? (y + 1) : 127;
    float4 cc = ip4[(yc << 5) + xq];
    if (y + 1 >= 128) { cc.x = 0.f; cc.y = 0.f; cc.z = 0.f; cc.w = 0.f; }
    float cL = __shfl_up(cc.w, 1);  if (xq == 0)  cL = 0.f;
    float cR = __shfl_down(cc.x, 1); if (xq == 31) cR = 0.f;

    float4 o;
    o.x = w0 * aL  + w1 * a.x + w2 * a.y +
          w3 * bL  + w4 * bb.x + w5 * bb.y +
          w6 * cL  + w7 * cc.x + w8 * cc.y;
    o.y = w0 * a.x + w1 * a.y + w2 * a.z +
          w3 * bb.x + w4 * bb.y + w5 * bb.z +
          w6 * cc.x + w7 * cc.y + w8 * cc.z;
    o.z = w0 * a.y + w1 * a.z + w2 * a.w +
          w3 * bb.y + w4 * bb.z + w5 * bb.w +
          w6 * cc.y + w7 * cc.z + w8 * cc.w;
    o.w = w0 * a.z + w1 * a.w + w2 * aR +
          w3 * bb.z + w4 * bb.w + w5 * bR +
          w6 * cc.z + w7 * cc.w + w8 * cR;

    op4[(y << 5) + xq] = o;
    ss += o.x * o.x + o.y * o.y + o.z * o.z + o.w * o.w;

    a = bb; aL = bL; aR = bR;
    bb = cc; bL = cL; bR = cR;
  }

  if (ssq) {
    #pragma unroll
    for (int off = 32; off > 0; off >>= 1) ss += __shfl_down(ss, off);
    __shared__ float red[4];
    if ((t & 63) == 0) red[t >> 6] = ss;
    __syncthreads();
    if (t == 0) ssq[b * 256 + c] = red[0] + red[1] + red[2] + red[3];
  }
}

// ---------------------------------------------------------------------------
// S[b,h,c,d] += sum_p qdw[b,h*32+c,p] * kdw[b,h*32+d,p]  (unnormalized Gram)
// MFMA split-K, hi/lo bf16 decomposition; no LDS staging in the main loop.
__global__ __launch_bounds__(256) void gram_kernel(
    const float* __restrict__ qdw, const float* __restrict__ kdw,
    float* __restrict__ S)
{
  int chunk = blockIdx.x, h = blockIdx.y, b = blockIdx.z;
  int t = threadIdx.x;
  int w = t >> 6, l = t & 63;
  int lm = l & 15;
  int lk8 = (l >> 4) * 8;

  const float* qh = qdw + (((size_t)b * 256 + h * 32) << 14);
  const float* kh = kdw + (((size_t)b * 256 + h * 32) << 14);
  const float* q0 = qh + ((size_t)lm << 14);
  const float* q1 = q0 + ((size_t)16 << 14);
  const float* k0 = kh + ((size_t)lm << 14);
  const float* k1 = k0 + ((size_t)16 << 14);

  int px0 = chunk * 1024 + w * 256 + lk8;

  f32x4 acc[2][2], accl[2][2];
  #pragma unroll
  for (int mi = 0; mi < 2; ++mi)
    #pragma unroll
    for (int nj = 0; nj < 2; ++nj) {
      acc[mi][nj] = {0.f, 0.f, 0.f, 0.f};
      accl[mi][nj] = {0.f, 0.f, 0.f, 0.f};
    }

  #pragma unroll 2
  for (int s = 0; s < 8; ++s) {
    int px = px0 + s * 32;
    float4 a0 = *(const float4*)(q0 + px);
    float4 a1 = *(const float4*)(q0 + px + 4);
    float4 a2 = *(const float4*)(q1 + px);
    float4 a3 = *(const float4*)(q1 + px + 4);
    float4 b0 = *(const float4*)(k0 + px);
    float4 b1 = *(const float4*)(k0 + px + 4);
    float4 b2 = *(const float4*)(k1 + px);
    float4 b3 = *(const float4*)(k1 + px + 4);

    bfrag qhF[2], qlF[2], khF[2], klF[2];
    cvt_hilo(a0, a1, qhF[0], qlF[0]);
    cvt_hilo(a2, a3, qhF[1], qlF[1]);
    cvt_hilo(b0, b1, khF[0], klF[0]);
    cvt_hilo(b2, b3, khF[1], klF[1]);

    #pragma unroll
    for (int mi = 0; mi < 2; ++mi)
      #pragma unroll
      for (int nj = 0; nj < 2; ++nj) {
        acc[mi][nj] = __builtin_amdgcn_mfma_f32_16x16x32_bf16(
            qhF[mi], khF[nj], acc[mi][nj], 0, 0, 0);
        accl[mi][nj] = __builtin_amdgcn_mfma_f32_16x16x32_bf16(
            qhF[mi], klF[nj], accl[mi][nj], 0, 0, 0);
        accl[mi][nj] = __builtin_amdgcn_mfma_f32_16x16x32_bf16(
            qlF[mi], khF[nj], accl[mi][nj], 0, 0, 0);
      }
  }

  // reduce the 4 waves' partial 32x32 tiles through LDS, then one
  // atomicAdd per element per block (16 adds/address across the grid).
  __shared__ float red[4][1024];
  int orow = (l >> 4) * 4;
  #pragma unroll
  for (int mi = 0; mi < 2; ++mi)
    #pragma unroll
    for (int nj = 0; nj < 2; ++nj)
      #pragma unroll
      for (int r = 0; r < 4; ++r)
        red[w][(mi * 16 + orow + r) * 32 + nj * 16 + lm] =
            acc[mi][nj][r] + accl[mi][nj][r];
  __syncthreads();
  float* Sp = S + (((size_t)b * 8 + h) << 10);
  for (int idx = t; idx < 1024; idx += 256)
    atomicAdd(&Sp[idx], red[0][idx] + red[1][idx] + red[2][idx] + red[3][idx]);
}

// ---------------------------------------------------------------------------
// FUSED softmax + mbuild (one dispatch instead of two):
// block (o,b): softmax S[b] into LDS (identical f32 math to the old
// softmax_kernel; redundant per-o but trivial), then
// M[b][o][h*32+d] = sum_c w_proj[o][h*32+c] * attn[b,h,c,d].
// At rows padded to 33 floats to spread LDS banks.
__global__ __launch_bounds__(256) void softmax_mbuild(
    const float* __restrict__ S, const float* __restrict__ ssq,
    const float* __restrict__ ssk, const float* __restrict__ temp,
    const float* __restrict__ wproj, float* __restrict__ M)
{
  int o = blockIdx.x, b = blockIdx.y;
  int t = threadIdx.x;
  __shared__ float At[8 * 32 * 33];   // [h][c][d] padded, 33.8 KB
  __shared__ float Iq[256], Ik[256], Wp[256];

  Iq[t] = 1.f / fmaxf(sqrtf(ssq[b * 256 + t]), 1e-12f);
  Ik[t] = 1.f / fmaxf(sqrtf(ssk[b * 256 + t]), 1e-12f);
  Wp[t] = wproj[o * 256 + t];
  __syncthreads();

  int h = t >> 5, c = t & 31;
  const float* row = S + (((size_t)b * 8 + h) << 10) + c * 32;
  float invq = Iq[h * 32 + c];
  float T = temp[h];
  float lg[32];
  float mx = -1e30f;
  #pragma unroll
  for (int d = 0; d < 32; ++d) {
    float v = row[d] * invq * Ik[h * 32 + d] * T;
    lg[d] = v;
    mx = fmaxf(mx, v);
  }
  float sum = 0.f;
  #pragma unroll
  for (int d = 0; d < 32; ++d) { float e = expf(lg[d] - mx); lg[d] = e; sum += e; }
  float inv = 1.f / sum;
  float* arow = &At[(h * 32 + c) * 33];
  #pragma unroll
  for (int d = 0; d < 32; ++d) arow[d] = lg[d] * inv;
  __syncthreads();

  // mbuild: col = t -> (h, d)
  int d2 = t & 31, h2 = t >> 5;
  float s = 0.f;
  #pragma unroll
  for (int cc = 0; cc < 32; ++cc)
    s += Wp[h2 * 32 + cc] * At[(h2 * 32 + cc) * 33 + d2];
  M[((size_t)b * 256 + o) * 256 + t] = s;
}

// ---------------------------------------------------------------------------
extern "C" void kernel_launch(void* const* d_in, const int* in_sizes, int n_in,
                              void* d_out, int out_size, void* d_ws, size_t ws_size,
                              hipStream_t stream)
{
  const float* x      = (const float*)d_in[0];
  const float* k_v    = (const float*)d_in[1];
  const float* temp   = (const float*)d_in[2];
  const float* w_kR   = (const float*)d_in[3];
  const float* w_kI   = (const float*)d_in[4];
  const float* w_qR   = (const float*)d_in[5];
  const float* w_qdw  = (const float*)d_in[6];
  const float* w_kvI  = (const float*)d_in[7];
  const float* w_kvdw = (const float*)d_in[8];
  const float* w_proj = (const float*)d_in[9];
  float* out = (float*)d_out;

  float* ws   = (float*)d_ws;
  float* bufA = ws;                 // 64 MB
  float* bufB = ws + 16777216;      // 64 MB
  float* bufC = ws + 33554432;      // 64 MB
  float* sm   = ws + 50331648;      // small region at 192 MB
  float* mod  = sm;                 // 1024
  float* ssq  = sm + 1024;          // 1024 (q norms^2, plain store)
  float* ssk  = sm + 2048;          // 1024 (k norms^2, plain store)
  float* S    = sm + 3072;          // 32768 (Gram -> attn via softmax_mbuild)
  float* M    = sm + 3072 + 32768;  // 262144 (fused attn+proj matrix)

  // mod + S-zeroing (replaces memset dispatch)
  mod_kernel<<<dim3(4), dim3(256), 0, stream>>>(k_v, w_kR, w_kI, mod, S);

  // q_pre -> bufA ; k_pre -> bufB  (merged launch, 2048 blocks)
  mgemm_qk<<<dim3(128, 4, 4), dim3(256), 0, stream>>>(
      w_qR, w_kvI, x, mod, bufA, bufB);

  // kdw -> bufC (+ k norms)
  dwconv_kernel<<<dim3(256, 4), dim3(256), 0, stream>>>(
      bufB, 4194304, w_kvdw, bufC, 4194304, ssk);

  // qdw -> bufB (+ q norms; k_pre dead)
  dwconv_kernel<<<dim3(256, 4), dim3(256), 0, stream>>>(
      bufA, 4194304, w_qdw, bufB, 4194304, ssq);

  // Gram: S = qdw . kdw^T over pixels
  gram_kernel<<<dim3(16, 8, 4), dim3(256), 0, stream>>>(bufB, bufC, S);

  // v_pre -> bufA (q_pre dead)
  mgemm<<<dim3(128, 2, 4), dim3(256), 0, stream>>>(
      w_kvI + 256 * 64, 64, 0, x, 192, 4194304, mod, bufA, 4194304, 64);

  // softmax + M = w_proj @ blockdiag(attn), one dispatch
  softmax_mbuild<<<dim3(256, 4), dim3(256), 0, stream>>>(
      S, ssq, ssk, temp, w_proj, M);

  // vdw -> bufC (kdw dead after gram)
  dwconv_kernel<<<dim3(256, 4), dim3(256), 0, stream>>>(
      bufA, 4194304, w_kvdw + 256 * 9, bufC, 4194304, (float*)nullptr);

  // out = M[b] @ vdw[b]
  mgemm<<<dim3(128, 2, 4), dim3(256), 0, stream>>>(
      M, 256, 65536, bufC, 0, 4194304, (const float*)nullptr, out, 4194304, 256);
}

// Round 9
// 319.924 us; speedup vs baseline: 1.7536x; 1.0001x over previous
//
#include <hip/hip_runtime.h>
#include <math.h>

#define HW 16384

typedef unsigned int uint;
typedef short bfrag __attribute__((ext_vector_type(8)));   // 8 bf16 (4 VGPRs)
typedef float f32x4 __attribute__((ext_vector_type(4)));   // 4 fp32 acc

union FragCvt { uint4 u; bfrag v; };

// round-to-nearest-even f32 -> bf16, pack two into a dword
__device__ inline uint pack2bf(float a, float b) {
  uint ua = __builtin_bit_cast(uint, a);
  uint ub = __builtin_bit_cast(uint, b);
  ua = (ua + 0x7FFFu + ((ua >> 16) & 1u)) >> 16;
  ub = (ub + 0x7FFFu + ((ub >> 16) & 1u)) & 0xFFFF0000u;
  return ua | ub;
}

// split 8 f32 into hi-bf16 frag and lo-bf16 frag (hi = RNE(x), lo = RNE(x-hi))
__device__ inline void cvt_hilo(float4 a, float4 b, bfrag& hi, bfrag& lo) {
  float v0[8] = {a.x, a.y, a.z, a.w, b.x, b.y, b.z, b.w};
  uint hv[4], lv[4];
  #pragma unroll
  for (int i = 0; i < 4; ++i) {
    float x0 = v0[2 * i], x1 = v0[2 * i + 1];
    uint h = pack2bf(x0, x1);
    float h0 = __builtin_bit_cast(float, h << 16);
    float h1 = __builtin_bit_cast(float, h & 0xFFFF0000u);
    hv[i] = h;
    lv[i] = pack2bf(x0 - h0, x1 - h1);
  }
  FragCvt ch, cl;
  ch.u = make_uint4(hv[0], hv[1], hv[2], hv[3]);
  cl.u = make_uint4(lv[0], lv[1], lv[2], lv[3]);
  hi = ch.v;
  lo = cl.v;
}

// LDS-only barrier: waits for this wave's LDS ops (lgkmcnt) but lets global
// loads (vmcnt) stay in flight across the barrier.
#define LDS_BARRIER() do { \
  asm volatile("s_waitcnt lgkmcnt(0)" ::: "memory"); \
  __builtin_amdgcn_s_barrier(); \
} while (0)

// ---------------------------------------------------------------------------
// mod[b,c] = 1 + (k_v @ w.T); also zeroes S (replaces the memset dispatch).
__global__ __launch_bounds__(256) void mod_kernel(
    const float* __restrict__ kv, const float* __restrict__ wkR,
    const float* __restrict__ wkI, float* __restrict__ mod,
    float* __restrict__ S)
{
  int b = blockIdx.x;
  int c = threadIdx.x;
  float4 z4 = make_float4(0.f, 0.f, 0.f, 0.f);
  float4* sp = (float4*)(S + (((size_t)b * 256 + c) << 5));
  #pragma unroll
  for (int i = 0; i < 8; ++i) sp[i] = z4;

  const float* kvb = kv + b * 256;
  float s = 0.f;
  if (c < 192) {
    const float* wr = wkR + c * 192;
    for (int j = 0; j < 192; ++j) s += kvb[j] * wr[j];
  } else {
    const float* wi = wkI + (c - 192) * 64;
    for (int j = 0; j < 64; ++j) s += kvb[192 + j] * wi[j];
  }
  mod[b * 256 + c] = 1.f + s;
}

// ---------------------------------------------------------------------------
// NEW GEMM body (q/k/v projections): W-tile (128 x K, ldW==K contiguous)
// staged ONCE into LDS as bf16 (stride Kp=K+8); Bl double-buffered so the
// K-loop has exactly ONE LDS barrier per 32-k step. X loads depth-2
// prefetched; vmcnt never drained at barriers (LDS_BARRIER).
// Bit-identical arithmetic to the previous version.
__device__ __forceinline__ void mgemm_body2(
    const float* __restrict__ Wt,      // 128 x K contiguous
    const float* __restrict__ Xt,      // X + b*bstride + c0*HW + nt*128
    const float* __restrict__ modc,    // mod + b*256 + c0 (non-null here)
    float* __restrict__ Yt,
    int K, int Kp, int t,
    unsigned short* Wl, unsigned short* Bl, float* Ml)
{
  int w = t >> 6, l = t & 63;
  int wm = (w >> 1) * 64, wn = (w & 1) * 64;   // outch base / pixel base
  int lm = l & 15, lk = (l >> 4) * 8;
  int bn = t & 127, bo = (t >> 7) * 8;

  Ml[t] = (t < K) ? modc[t] : 1.f;

  // ---- stage whole W tile -> bf16 LDS (once). Contiguous copy, RNE pack.
  {
    int total = 128 * K;
    for (int base = t * 8; base < total; base += 2048) {
      int row = base / K;
      int kk = base - row * K;
      const float* src = Wt + base;
      float4 a0 = *(const float4*)(src);
      float4 a1 = *(const float4*)(src + 4);
      uint4 pw;
      pw.x = pack2bf(a0.x, a0.y); pw.y = pack2bf(a0.z, a0.w);
      pw.z = pack2bf(a1.x, a1.y); pw.w = pack2bf(a1.z, a1.w);
      *(uint4*)&Wl[row * Kp + kk] = pw;
    }
  }

  f32x4 acc[4][4];
  #pragma unroll
  for (int fi = 0; fi < 4; ++fi)
    #pragma unroll
    for (int fj = 0; fj < 4; ++fj) acc[fi][fj] = {0.f, 0.f, 0.f, 0.f};

  float xrA[16], xrB[16];
  auto load_x = [&](float* xr, int k0) {
    #pragma unroll
    for (int i = 0; i < 2; ++i) {
      int kb = k0 + bo + i * 16;
      #pragma unroll
      for (int r = 0; r < 8; ++r)
        xr[i * 8 + r] = Xt[(size_t)(kb + r) * HW + bn];
    }
  };
  auto pack_b = [&](const float* xr, int k0, unsigned short* blp) {
    #pragma unroll
    for (int i = 0; i < 2; ++i) {
      float4 m0 = *(const float4*)&Ml[k0 + bo + i * 16];
      float4 m1 = *(const float4*)&Ml[k0 + bo + i * 16 + 4];
      uint4 bw;
      bw.x = pack2bf(xr[i * 8 + 0] * m0.x, xr[i * 8 + 1] * m0.y);
      bw.y = pack2bf(xr[i * 8 + 2] * m0.z, xr[i * 8 + 3] * m0.w);
      bw.z = pack2bf(xr[i * 8 + 4] * m1.x, xr[i * 8 + 5] * m1.y);
      bw.w = pack2bf(xr[i * 8 + 6] * m1.z, xr[i * 8 + 7] * m1.w);
      *(uint4*)&blp[bn * 40 + bo + i * 16] = bw;
    }
  };
  auto mfma_step = [&](int k0, const unsigned short* blp) {
    bfrag af[4], bfr[4];
    #pragma unroll
    for (int fj = 0; fj < 4; ++fj) {
      FragCvt cv;
      cv.u = *(const uint4*)&Wl[(wm + fj * 16 + lm) * Kp + k0 + lk];
      af[fj] = cv.v;
    }
    #pragma unroll
    for (int fi = 0; fi < 4; ++fi) {
      FragCvt cv;
      cv.u = *(const uint4*)&blp[(wn + fi * 16 + lm) * 40 + lk];
      bfr[fi] = cv.v;
    }
    #pragma unroll
    for (int fi = 0; fi < 4; ++fi)
      #pragma unroll
      for (int fj = 0; fj < 4; ++fj)
        acc[fi][fj] = __builtin_amdgcn_mfma_f32_16x16x32_bf16(
            bfr[fi], af[fj], acc[fi][fj], 0, 0, 0);
  };

  // issue X prefetches AFTER the W staging loads so vmcnt waits inside the
  // staging don't drain them; they stay in flight across the barrier.
  load_x(xrA, 0);
  load_x(xrB, 32);

  LDS_BARRIER();   // Wl + Ml visible to all waves

  unsigned short* bl0 = Bl;
  unsigned short* bl1 = Bl + 128 * 40;
  for (int k0 = 0; k0 < K; k0 += 64) {
    // step A (k0): write bl0, read bl0
    pack_b(xrA, k0, bl0);
    if (k0 + 64 < K) load_x(xrA, k0 + 64);
    LDS_BARRIER();
    mfma_step(k0, bl0);

    // step B (k0+32): write bl1, read bl1 (bl0 reads completed at next barrier)
    pack_b(xrB, k0 + 32, bl1);
    if (k0 + 96 < K) load_x(xrB, k0 + 96);
    LDS_BARRIER();
    mfma_step(k0 + 32, bl1);
  }

  int ph = (l >> 4) * 4;
  #pragma unroll
  for (int fi = 0; fi < 4; ++fi)
    #pragma unroll
    for (int fj = 0; fj < 4; ++fj)
      *(f32x4*)&Yt[(size_t)(wm + fj * 16 + lm) * HW + wn + fi * 16 + ph] =
          acc[fi][fj];
}

// merged q (mt 0-1, K=192) + k (mt 2-3, K=64) projections, new body
__global__ __launch_bounds__(256, 2) void mgemm_qk(
    const float* __restrict__ wqR, const float* __restrict__ wkvI,
    const float* __restrict__ X, const float* __restrict__ mod,
    float* __restrict__ Yq, float* __restrict__ Yk)
{
  __shared__ unsigned short Wl[128 * 200];   // 50 KB (K=192, Kp=200)
  __shared__ unsigned short Bl[2 * 128 * 40];
  __shared__ float Ml[256];
  int b = blockIdx.z, mt = blockIdx.y, nt = blockIdx.x;
  if (mt < 2) {
    mgemm_body2(wqR + (size_t)mt * 128 * 192,
                X + (size_t)b * 4194304 + nt * 128,
                mod + b * 256,
                Yq + (size_t)b * 4194304 + (size_t)mt * 128 * HW + nt * 128,
                192, 200, threadIdx.x, Wl, Bl, Ml);
  } else {
    int m2 = mt - 2;
    mgemm_body2(wkvI + (size_t)m2 * 128 * 64,
                X + (size_t)b * 4194304 + (size_t)192 * HW + nt * 128,
                mod + b * 256 + 192,
                Yk + (size_t)b * 4194304 + (size_t)m2 * 128 * HW + nt * 128,
                64, 72, threadIdx.x, Wl, Bl, Ml);
  }
}

// v projection (K=64), new body, small LDS -> higher occupancy
__global__ __launch_bounds__(256, 4) void mgemm_k64(
    const float* __restrict__ W, const float* __restrict__ X, int c0,
    const float* __restrict__ mod, float* __restrict__ Y)
{
  __shared__ unsigned short Wl[128 * 72];    // 18 KB
  __shared__ unsigned short Bl[2 * 128 * 40];
  __shared__ float Ml[256];
  int b = blockIdx.z, mt = blockIdx.y, nt = blockIdx.x;
  mgemm_body2(W + (size_t)mt * 128 * 64,
              X + (size_t)b * 4194304 + (size_t)c0 * HW + nt * 128,
              mod + b * 256 + c0,
              Y + (size_t)b * 4194304 + (size_t)mt * 128 * HW + nt * 128,
              64, 72, threadIdx.x, Wl, Bl, Ml);
}

// ---------------------------------------------------------------------------
// OLD GEMM body, kept for the out-gemm (K=256, per-batch W, no mod).
__device__ __forceinline__ void mgemm_body(
    const float* __restrict__ Wt, int ldW,
    const float* __restrict__ Xt,
    const float* __restrict__ modc,
    float* __restrict__ Yt,
    int K, int t, unsigned short* Al, unsigned short* Bl, float* Ml)
{
  int w = t >> 6, l = t & 63;
  int wm = (w >> 1) * 64, wn = (w & 1) * 64;
  int lm = l & 15, lk = (l >> 4) * 8;

  int am = t >> 1, ako = (t & 1) * 16;
  int bn = t & 127, bo = (t >> 7) * 8;

  Ml[t] = (modc && t < K) ? modc[t] : 1.f;

  f32x4 acc[4][4];
  #pragma unroll
  for (int fi = 0; fi < 4; ++fi)
    #pragma unroll
    for (int fj = 0; fj < 4; ++fj) acc[fi][fj] = {0.f, 0.f, 0.f, 0.f};

  float xrA[16], xrB[16];
  float4 wv0, wv1, wv2, wv3;

  auto load_x = [&](float* xr, int k0) {
    #pragma unroll
    for (int i = 0; i < 2; ++i) {
      int kb = k0 + bo + i * 16;
      #pragma unroll
      for (int r = 0; r < 8; ++r)
        xr[i * 8 + r] = Xt[(size_t)(kb + r) * HW + bn];
    }
  };
  auto load_w = [&](int k0) {
    const float* wsrc = Wt + (size_t)am * ldW + k0 + ako;
    wv0 = *(const float4*)(wsrc);
    wv1 = *(const float4*)(wsrc + 4);
    wv2 = *(const float4*)(wsrc + 8);
    wv3 = *(const float4*)(wsrc + 12);
  };
  auto pack_a = [&]() {
    uint4 aw0, aw1;
    aw0.x = pack2bf(wv0.x, wv0.y); aw0.y = pack2bf(wv0.z, wv0.w);
    aw0.z = pack2bf(wv1.x, wv1.y); aw0.w = pack2bf(wv1.z, wv1.w);
    aw1.x = pack2bf(wv2.x, wv2.y); aw1.y = pack2bf(wv2.z, wv2.w);
    aw1.z = pack2bf(wv3.x, wv3.y); aw1.w = pack2bf(wv3.z, wv3.w);
    *(uint4*)&Al[am * 40 + ako] = aw0;
    *(uint4*)&Al[am * 40 + ako + 8] = aw1;
  };
  auto pack_b = [&](const float* xr, int k0) {
    #pragma unroll
    for (int i = 0; i < 2; ++i) {
      float4 m0 = *(const float4*)&Ml[k0 + bo + i * 16];
      float4 m1 = *(const float4*)&Ml[k0 + bo + i * 16 + 4];
      uint4 bw;
      bw.x = pack2bf(xr[i * 8 + 0] * m0.x, xr[i * 8 + 1] * m0.y);
      bw.y = pack2bf(xr[i * 8 + 2] * m0.z, xr[i * 8 + 3] * m0.w);
      bw.z = pack2bf(xr[i * 8 + 4] * m1.x, xr[i * 8 + 5] * m1.y);
      bw.w = pack2bf(xr[i * 8 + 6] * m1.z, xr[i * 8 + 7] * m1.w);
      *(uint4*)&Bl[bn * 40 + bo + i * 16] = bw;
    }
  };
  auto mfma_step = [&]() {
    bfrag af[4], bfr[4];
    #pragma unroll
    for (int fj = 0; fj < 4; ++fj) {
      FragCvt cv;
      cv.u = *(const uint4*)&Al[(wm + fj * 16 + lm) * 40 + lk];
      af[fj] = cv.v;
    }
    #pragma unroll
    for (int fi = 0; fi < 4; ++fi) {
      FragCvt cv;
      cv.u = *(const uint4*)&Bl[(wn + fi * 16 + lm) * 40 + lk];
      bfr[fi] = cv.v;
    }
    #pragma unroll
    for (int fi = 0; fi < 4; ++fi)
      #pragma unroll
      for (int fj = 0; fj < 4; ++fj)
        acc[fi][fj] = __builtin_amdgcn_mfma_f32_16x16x32_bf16(
            bfr[fi], af[fj], acc[fi][fj], 0, 0, 0);
  };

  load_x(xrA, 0);
  load_x(xrB, 32);
  load_w(0);

  for (int k0 = 0; k0 < K; k0 += 64) {
    LDS_BARRIER();
    pack_a();
    if (k0 + 32 < K) load_w(k0 + 32);
    pack_b(xrA, k0);
    if (k0 + 64 < K) load_x(xrA, k0 + 64);
    LDS_BARRIER();
    mfma_step();

    LDS_BARRIER();
    pack_a();
    if (k0 + 64 < K) load_w(k0 + 64);
    pack_b(xrB, k0 + 32);
    if (k0 + 96 < K) load_x(xrB, k0 + 96);
    LDS_BARRIER();
    mfma_step();
  }

  int ph = (l >> 4) * 4;
  #pragma unroll
  for (int fi = 0; fi < 4; ++fi)
    #pragma unroll
    for (int fj = 0; fj < 4; ++fj)
      *(f32x4*)&Yt[(size_t)(wm + fj * 16 + lm) * HW + wn + fi * 16 + ph] =
          acc[fi][fj];
}

__global__ __launch_bounds__(256, 2) void mgemm(
    const float* __restrict__ W, int ldW, size_t Wbstride,
    const float* __restrict__ X, int c0, size_t Xbstride,
    const float* __restrict__ mod,
    float* __restrict__ Y, size_t Ybstride, int K)
{
  __shared__ unsigned short Al[128 * 40];
  __shared__ unsigned short Bl[128 * 40];
  __shared__ float Ml[256];
  int b = blockIdx.z, mt = blockIdx.y, nt = blockIdx.x;
  mgemm_body(W + (size_t)b * Wbstride + (size_t)mt * 128 * ldW, ldW,
             X + (size_t)b * Xbstride + (size_t)c0 * HW + nt * 128,
             mod ? mod + b * 256 + c0 : (const float*)nullptr,
             Y + (size_t)b * Ybstride + (size_t)mt * 128 * HW + nt * 128,
             K, threadIdx.x, Al, Bl, Ml);
}

// ---------------------------------------------------------------------------
// depthwise 3x3, SAME zero pad. One block per (channel, batch).
__global__ __launch_bounds__(256) void dwconv_kernel(
    const float* __restrict__ in, size_t in_bstride,
    const float* __restrict__ wdw,
    float* __restrict__ out, size_t out_bstride,
    float* __restrict__ ssq)
{
  int c = blockIdx.x;
  int b = blockIdx.y;
  int t = threadIdx.x;
  int r = t >> 5;
  int xq = t & 31;

  const float4* ip4 = (const float4*)(in + (size_t)b * in_bstride + ((size_t)c << 14));
  float4* op4 = (float4*)(out + (size_t)b * out_bstride + ((size_t)c << 14));
  const float* wp = wdw + c * 9;
  float w0 = wp[0], w1 = wp[1], w2 = wp[2], w3 = wp[3], w4 = wp[4],
        w5 = wp[5], w6 = wp[6], w7 = wp[7], w8 = wp[8];

  const float4 z4 = make_float4(0.f, 0.f, 0.f, 0.f);
  int y0 = r << 4;

  float4 a = (y0 > 0) ? ip4[((y0 - 1) << 5) + xq] : z4;
  float4 bb = ip4[(y0 << 5) + xq];

  float aL = __shfl_up(a.w, 1);  if (xq == 0)  aL = 0.f;
  float aR = __shfl_down(a.x, 1); if (xq == 31) aR = 0.f;
  float bL = __shfl_up(bb.w, 1); if (xq == 0)  bL = 0.f;
  float bR = __shfl_down(bb.x, 1); if (xq == 31) bR = 0.f;

  float ss = 0.f;
  #pragma unroll
  for (int i = 0; i < 16; ++i) {
    int y = y0 + i;
    int yc = (y + 1 < 128) ? (y + 1) : 127;
    float4 cc = ip4[(yc << 5) + xq];
    if (y + 1 >= 128) { cc.x = 0.f; cc.y = 0.f; cc.z = 0.f; cc.w = 0.f; }
    float cL = __shfl_up(cc.w, 1);  if (xq == 0)  cL = 0.f;
    float cR = __shfl_down(cc.x, 1); if (xq == 31) cR = 0.f;

    float4 o;
    o.x = w0 * aL  + w1 * a.x + w2 * a.y +
          w3 * bL  + w4 * bb.x + w5 * bb.y +
          w6 * cL  + w7 * cc.x + w8 * cc.y;
    o.y = w0 * a.x + w1 * a.y + w2 * a.z +
          w3 * bb.x + w4 * bb.y + w5 * bb.z +
          w6 * cc.x + w7 * cc.y + w8 * cc.z;
    o.z = w0 * a.y + w1 * a.z + w2 * a.w +
          w3 * bb.y + w4 * bb.z + w5 * bb.w +
          w6 * cc.y + w7 * cc.z + w8 * cc.w;
    o.w = w0 * a.z + w1 * a.w + w2 * aR +
          w3 * bb.z + w4 * bb.w + w5 * bR +
          w6 * cc.z + w7 * cc.w + w8 * cR;

    op4[(y << 5) + xq] = o;
    ss += o.x * o.x + o.y * o.y + o.z * o.z + o.w * o.w;

    a = bb; aL = bL; aR = bR;
    bb = cc; bL = cL; bR = cR;
  }

  if (ssq) {
    #pragma unroll
    for (int off = 32; off > 0; off >>= 1) ss += __shfl_down(ss, off);
    __shared__ float red[4];
    if ((t & 63) == 0) red[t >> 6] = ss;
    __syncthreads();
    if (t == 0) ssq[b * 256 + c] = red[0] + red[1] + red[2] + red[3];
  }
}

// ---------------------------------------------------------------------------
// S[b,h,c,d] += sum_p qdw[b,h*32+c,p] * kdw[b,h*32+d,p]  (unnormalized Gram)
// MFMA split-K, hi/lo bf16 decomposition; no LDS staging in the main loop.
__global__ __launch_bounds__(256) void gram_kernel(
    const float* __restrict__ qdw, const float* __restrict__ kdw,
    float* __restrict__ S)
{
  int chunk = blockIdx.x, h = blockIdx.y, b = blockIdx.z;
  int t = threadIdx.x;
  int w = t >> 6, l = t & 63;
  int lm = l & 15;
  int lk8 = (l >> 4) * 8;

  const float* qh = qdw + (((size_t)b * 256 + h * 32) << 14);
  const float* kh = kdw + (((size_t)b * 256 + h * 32) << 14);
  const float* q0 = qh + ((size_t)lm << 14);
  const float* q1 = q0 + ((size_t)16 << 14);
  const float* k0 = kh + ((size_t)lm << 14);
  const float* k1 = k0 + ((size_t)16 << 14);

  int px0 = chunk * 1024 + w * 256 + lk8;

  f32x4 acc[2][2], accl[2][2];
  #pragma unroll
  for (int mi = 0; mi < 2; ++mi)
    #pragma unroll
    for (int nj = 0; nj < 2; ++nj) {
      acc[mi][nj] = {0.f, 0.f, 0.f, 0.f};
      accl[mi][nj] = {0.f, 0.f, 0.f, 0.f};
    }

  #pragma unroll 2
  for (int s = 0; s < 8; ++s) {
    int px = px0 + s * 32;
    float4 a0 = *(const float4*)(q0 + px);
    float4 a1 = *(const float4*)(q0 + px + 4);
    float4 a2 = *(const float4*)(q1 + px);
    float4 a3 = *(const float4*)(q1 + px + 4);
    float4 b0 = *(const float4*)(k0 + px);
    float4 b1 = *(const float4*)(k0 + px + 4);
    float4 b2 = *(const float4*)(k1 + px);
    float4 b3 = *(const float4*)(k1 + px + 4);

    bfrag qhF[2], qlF[2], khF[2], klF[2];
    cvt_hilo(a0, a1, qhF[0], qlF[0]);
    cvt_hilo(a2, a3, qhF[1], qlF[1]);
    cvt_hilo(b0, b1, khF[0], klF[0]);
    cvt_hilo(b2, b3, khF[1], klF[1]);

    #pragma unroll
    for (int mi = 0; mi < 2; ++mi)
      #pragma unroll
      for (int nj = 0; nj < 2; ++nj) {
        acc[mi][nj] = __builtin_amdgcn_mfma_f32_16x16x32_bf16(
            qhF[mi], khF[nj], acc[mi][nj], 0, 0, 0);
        accl[mi][nj] = __builtin_amdgcn_mfma_f32_16x16x32_bf16(
            qhF[mi], klF[nj], accl[mi][nj], 0, 0, 0);
        accl[mi][nj] = __builtin_amdgcn_mfma_f32_16x16x32_bf16(
            qlF[mi], khF[nj], accl[mi][nj], 0, 0, 0);
      }
  }

  __shared__ float red[4][1024];
  int orow = (l >> 4) * 4;
  #pragma unroll
  for (int mi = 0; mi < 2; ++mi)
    #pragma unroll
    for (int nj = 0; nj < 2; ++nj)
      #pragma unroll
      for (int r = 0; r < 4; ++r)
        red[w][(mi * 16 + orow + r) * 32 + nj * 16 + lm] =
            acc[mi][nj][r] + accl[mi][nj][r];
  __syncthreads();
  float* Sp = S + (((size_t)b * 8 + h) << 10);
  for (int idx = t; idx < 1024; idx += 256)
    atomicAdd(&Sp[idx], red[0][idx] + red[1][idx] + red[2][idx] + red[3][idx]);
}

// ---------------------------------------------------------------------------
// FUSED softmax + mbuild: block (o,b) softmaxes S[b] into LDS then computes
// M[b][o][h*32+d] = sum_c w_proj[o][h*32+c] * attn[b,h,c,d].
__global__ __launch_bounds__(256) void softmax_mbuild(
    const float* __restrict__ S, const float* __restrict__ ssq,
    const float* __restrict__ ssk, const float* __restrict__ temp,
    const float* __restrict__ wproj, float* __restrict__ M)
{
  int o = blockIdx.x, b = blockIdx.y;
  int t = threadIdx.x;
  __shared__ float At[8 * 32 * 33];
  __shared__ float Iq[256], Ik[256], Wp[256];

  Iq[t] = 1.f / fmaxf(sqrtf(ssq[b * 256 + t]), 1e-12f);
  Ik[t] = 1.f / fmaxf(sqrtf(ssk[b * 256 + t]), 1e-12f);
  Wp[t] = wproj[o * 256 + t];
  __syncthreads();

  int h = t >> 5, c = t & 31;
  const float* row = S + (((size_t)b * 8 + h) << 10) + c * 32;
  float invq = Iq[h * 32 + c];
  float T = temp[h];
  float lg[32];
  float mx = -1e30f;
  #pragma unroll
  for (int d = 0; d < 32; ++d) {
    float v = row[d] * invq * Ik[h * 32 + d] * T;
    lg[d] = v;
    mx = fmaxf(mx, v);
  }
  float sum = 0.f;
  #pragma unroll
  for (int d = 0; d < 32; ++d) { float e = expf(lg[d] - mx); lg[d] = e; sum += e; }
  float inv = 1.f / sum;
  float* arow = &At[(h * 32 + c) * 33];
  #pragma unroll
  for (int d = 0; d < 32; ++d) arow[d] = lg[d] * inv;
  __syncthreads();

  int d2 = t & 31, h2 = t >> 5;
  float s = 0.f;
  #pragma unroll
  for (int cc = 0; cc < 32; ++cc)
    s += Wp[h2 * 32 + cc] * At[(h2 * 32 + cc) * 33 + d2];
  M[((size_t)b * 256 + o) * 256 + t] = s;
}

// ---------------------------------------------------------------------------
extern "C" void kernel_launch(void* const* d_in, const int* in_sizes, int n_in,
                              void* d_out, int out_size, void* d_ws, size_t ws_size,
                              hipStream_t stream)
{
  const float* x      = (const float*)d_in[0];
  const float* k_v    = (const float*)d_in[1];
  const float* temp   = (const float*)d_in[2];
  const float* w_kR   = (const float*)d_in[3];
  const float* w_kI   = (const float*)d_in[4];
  const float* w_qR   = (const float*)d_in[5];
  const float* w_qdw  = (const float*)d_in[6];
  const float* w_kvI  = (const float*)d_in[7];
  const float* w_kvdw = (const float*)d_in[8];
  const float* w_proj = (const float*)d_in[9];
  float* out = (float*)d_out;

  float* ws   = (float*)d_ws;
  float* bufA = ws;                 // 64 MB
  float* bufB = ws + 16777216;      // 64 MB
  float* bufC = ws + 33554432;      // 64 MB
  float* sm   = ws + 50331648;      // small region at 192 MB
  float* mod  = sm;                 // 1024
  float* ssq  = sm + 1024;          // 1024 (q norms^2, plain store)
  float* ssk  = sm + 2048;          // 1024 (k norms^2, plain store)
  float* S    = sm + 3072;          // 32768 (Gram -> attn via softmax_mbuild)
  float* M    = sm + 3072 + 32768;  // 262144 (fused attn+proj matrix)

  // mod + S-zeroing (replaces memset dispatch)
  mod_kernel<<<dim3(4), dim3(256), 0, stream>>>(k_v, w_kR, w_kI, mod, S);

  // q_pre -> bufA ; k_pre -> bufB  (merged launch, new static-Wl body)
  mgemm_qk<<<dim3(128, 4, 4), dim3(256), 0, stream>>>(
      w_qR, w_kvI, x, mod, bufA, bufB);

  // kdw -> bufC (+ k norms)
  dwconv_kernel<<<dim3(256, 4), dim3(256), 0, stream>>>(
      bufB, 4194304, w_kvdw, bufC, 4194304, ssk);

  // qdw -> bufB (+ q norms; k_pre dead)
  dwconv_kernel<<<dim3(256, 4), dim3(256), 0, stream>>>(
      bufA, 4194304, w_qdw, bufB, 4194304, ssq);

  // Gram: S = qdw . kdw^T over pixels
  gram_kernel<<<dim3(16, 8, 4), dim3(256), 0, stream>>>(bufB, bufC, S);

  // v_pre -> bufA (q_pre dead)
  mgemm_k64<<<dim3(128, 2, 4), dim3(256), 0, stream>>>(
      w_kvI + 256 * 64, x, 192, mod, bufA);

  // softmax + M = w_proj @ blockdiag(attn), one dispatch
  softmax_mbuild<<<dim3(256, 4), dim3(256), 0, stream>>>(
      S, ssq, ssk, temp, w_proj, M);

  // vdw -> bufC (kdw dead after gram)
  dwconv_kernel<<<dim3(256, 4), dim3(256), 0, stream>>>(
      bufA, 4194304, w_kvdw + 256 * 9, bufC, 4194304, (float*)nullptr);

  // out = M[b] @ vdw[b]
  mgemm<<<dim3(128, 2, 4), dim3(256), 0, stream>>>(
      M, 256, 65536, bufC, 0, 4194304, (const float*)nullptr, out, 4194304, 256);
}

// Round 10
// 304.221 us; speedup vs baseline: 1.8441x; 1.0516x over previous
//
#include <hip/hip_runtime.h>
#include <math.h>

#define HW 16384

typedef unsigned int uint;
typedef short bfrag __attribute__((ext_vector_type(8)));   // 8 bf16 (4 VGPRs)
typedef float f32x4 __attribute__((ext_vector_type(4)));   // 4 fp32 acc

union FragCvt { uint4 u; bfrag v; };

// round-to-nearest-even f32 -> bf16, pack two into a dword
__device__ inline uint pack2bf(float a, float b) {
  uint ua = __builtin_bit_cast(uint, a);
  uint ub = __builtin_bit_cast(uint, b);
  ua = (ua + 0x7FFFu + ((ua >> 16) & 1u)) >> 16;
  ub = (ub + 0x7FFFu + ((ub >> 16) & 1u)) & 0xFFFF0000u;
  return ua | ub;
}

// split 8 f32 into hi-bf16 frag and lo-bf16 frag (hi = RNE(x), lo = RNE(x-hi))
__device__ inline void cvt_hilo(float4 a, float4 b, bfrag& hi, bfrag& lo) {
  float v0[8] = {a.x, a.y, a.z, a.w, b.x, b.y, b.z, b.w};
  uint hv[4], lv[4];
  #pragma unroll
  for (int i = 0; i < 4; ++i) {
    float x0 = v0[2 * i], x1 = v0[2 * i + 1];
    uint h = pack2bf(x0, x1);
    float h0 = __builtin_bit_cast(float, h << 16);
    float h1 = __builtin_bit_cast(float, h & 0xFFFF0000u);
    hv[i] = h;
    lv[i] = pack2bf(x0 - h0, x1 - h1);
  }
  FragCvt ch, cl;
  ch.u = make_uint4(hv[0], hv[1], hv[2], hv[3]);
  cl.u = make_uint4(lv[0], lv[1], lv[2], lv[3]);
  hi = ch.v;
  lo = cl.v;
}

// LDS-only barrier: waits for this wave's LDS ops (lgkmcnt) but lets global
// loads (vmcnt) stay in flight across the barrier.
#define LDS_BARRIER() do { \
  asm volatile("s_waitcnt lgkmcnt(0)" ::: "memory"); \
  __builtin_amdgcn_s_barrier(); \
} while (0)

// ---------------------------------------------------------------------------
// mod[b,c] = 1 + (k_v @ w.T); also zeroes S (replaces the memset dispatch).
__global__ __launch_bounds__(256) void mod_kernel(
    const float* __restrict__ kv, const float* __restrict__ wkR,
    const float* __restrict__ wkI, float* __restrict__ mod,
    float* __restrict__ S)
{
  int b = blockIdx.x;
  int c = threadIdx.x;
  float4 z4 = make_float4(0.f, 0.f, 0.f, 0.f);
  float4* sp = (float4*)(S + (((size_t)b * 256 + c) << 5));
  #pragma unroll
  for (int i = 0; i < 8; ++i) sp[i] = z4;

  const float* kvb = kv + b * 256;
  float s = 0.f;
  if (c < 192) {
    const float* wr = wkR + c * 192;
    for (int j = 0; j < 192; ++j) s += kvb[j] * wr[j];
  } else {
    const float* wi = wkI + (c - 192) * 64;
    for (int j = 0; j < 64; ++j) s += kvb[192 + j] * wi[j];
  }
  mod[b * 256 + c] = 1.f + s;
}

// ---------------------------------------------------------------------------
// GEMM body (R6-proven): Y[128 x 128px] = W[128,K] @ (X[k,:] * mod[k]).
// 4 waves 2x2, 4x4 frags 16x16x32, f32 accum. X depth-2 prefetch; W depth-1;
// LDS_BARRIER keeps global loads in flight across barriers.
__device__ __forceinline__ void mgemm_body(
    const float* __restrict__ Wt, int ldW,
    const float* __restrict__ Xt,
    const float* __restrict__ modc,
    float* __restrict__ Yt,
    int K, int t, unsigned short* Al, unsigned short* Bl, float* Ml)
{
  int w = t >> 6, l = t & 63;
  int wm = (w >> 1) * 64, wn = (w & 1) * 64;
  int lm = l & 15, lk = (l >> 4) * 8;

  int am = t >> 1, ako = (t & 1) * 16;
  int bn = t & 127, bo = (t >> 7) * 8;

  Ml[t] = (modc && t < K) ? modc[t] : 1.f;

  f32x4 acc[4][4];
  #pragma unroll
  for (int fi = 0; fi < 4; ++fi)
    #pragma unroll
    for (int fj = 0; fj < 4; ++fj) acc[fi][fj] = {0.f, 0.f, 0.f, 0.f};

  float xrA[16], xrB[16];
  float4 wv0, wv1, wv2, wv3;

  auto load_x = [&](float* xr, int k0) {
    #pragma unroll
    for (int i = 0; i < 2; ++i) {
      int kb = k0 + bo + i * 16;
      #pragma unroll
      for (int r = 0; r < 8; ++r)
        xr[i * 8 + r] = Xt[(size_t)(kb + r) * HW + bn];
    }
  };
  auto load_w = [&](int k0) {
    const float* wsrc = Wt + (size_t)am * ldW + k0 + ako;
    wv0 = *(const float4*)(wsrc);
    wv1 = *(const float4*)(wsrc + 4);
    wv2 = *(const float4*)(wsrc + 8);
    wv3 = *(const float4*)(wsrc + 12);
  };
  auto pack_a = [&]() {
    uint4 aw0, aw1;
    aw0.x = pack2bf(wv0.x, wv0.y); aw0.y = pack2bf(wv0.z, wv0.w);
    aw0.z = pack2bf(wv1.x, wv1.y); aw0.w = pack2bf(wv1.z, wv1.w);
    aw1.x = pack2bf(wv2.x, wv2.y); aw1.y = pack2bf(wv2.z, wv2.w);
    aw1.z = pack2bf(wv3.x, wv3.y); aw1.w = pack2bf(wv3.z, wv3.w);
    *(uint4*)&Al[am * 40 + ako] = aw0;
    *(uint4*)&Al[am * 40 + ako + 8] = aw1;
  };
  auto pack_b = [&](const float* xr, int k0) {
    #pragma unroll
    for (int i = 0; i < 2; ++i) {
      float4 m0 = *(const float4*)&Ml[k0 + bo + i * 16];
      float4 m1 = *(const float4*)&Ml[k0 + bo + i * 16 + 4];
      uint4 bw;
      bw.x = pack2bf(xr[i * 8 + 0] * m0.x, xr[i * 8 + 1] * m0.y);
      bw.y = pack2bf(xr[i * 8 + 2] * m0.z, xr[i * 8 + 3] * m0.w);
      bw.z = pack2bf(xr[i * 8 + 4] * m1.x, xr[i * 8 + 5] * m1.y);
      bw.w = pack2bf(xr[i * 8 + 6] * m1.z, xr[i * 8 + 7] * m1.w);
      *(uint4*)&Bl[bn * 40 + bo + i * 16] = bw;
    }
  };
  auto mfma_step = [&]() {
    bfrag af[4], bfr[4];
    #pragma unroll
    for (int fj = 0; fj < 4; ++fj) {
      FragCvt cv;
      cv.u = *(const uint4*)&Al[(wm + fj * 16 + lm) * 40 + lk];
      af[fj] = cv.v;
    }
    #pragma unroll
    for (int fi = 0; fi < 4; ++fi) {
      FragCvt cv;
      cv.u = *(const uint4*)&Bl[(wn + fi * 16 + lm) * 40 + lk];
      bfr[fi] = cv.v;
    }
    #pragma unroll
    for (int fi = 0; fi < 4; ++fi)
      #pragma unroll
      for (int fj = 0; fj < 4; ++fj)
        acc[fi][fj] = __builtin_amdgcn_mfma_f32_16x16x32_bf16(
            bfr[fi], af[fj], acc[fi][fj], 0, 0, 0);
  };

  load_x(xrA, 0);
  load_x(xrB, 32);
  load_w(0);

  for (int k0 = 0; k0 < K; k0 += 64) {
    LDS_BARRIER();
    pack_a();
    if (k0 + 32 < K) load_w(k0 + 32);
    pack_b(xrA, k0);
    if (k0 + 64 < K) load_x(xrA, k0 + 64);
    LDS_BARRIER();
    mfma_step();

    LDS_BARRIER();
    pack_a();
    if (k0 + 64 < K) load_w(k0 + 64);
    pack_b(xrB, k0 + 32);
    if (k0 + 96 < K) load_x(xrB, k0 + 96);
    LDS_BARRIER();
    mfma_step();
  }

  int ph = (l >> 4) * 4;
  #pragma unroll
  for (int fi = 0; fi < 4; ++fi)
    #pragma unroll
    for (int fj = 0; fj < 4; ++fj)
      *(f32x4*)&Yt[(size_t)(wm + fj * 16 + lm) * HW + wn + fi * 16 + ph] =
          acc[fi][fj];
}

// merged q (mt 0-1, K=192, c0=0) + k (mt 2-3, K=64, c0=192) projections
__global__ __launch_bounds__(256, 2) void mgemm_qk(
    const float* __restrict__ wqR, const float* __restrict__ wkvI,
    const float* __restrict__ X, const float* __restrict__ mod,
    float* __restrict__ Yq, float* __restrict__ Yk)
{
  __shared__ unsigned short Al[128 * 40];
  __shared__ unsigned short Bl[128 * 40];
  __shared__ float Ml[256];
  int b = blockIdx.z, mt = blockIdx.y, nt = blockIdx.x;
  if (mt < 2) {
    mgemm_body(wqR + (size_t)mt * 128 * 192, 192,
               X + (size_t)b * 4194304 + nt * 128,
               mod + b * 256,
               Yq + (size_t)b * 4194304 + (size_t)mt * 128 * HW + nt * 128,
               192, threadIdx.x, Al, Bl, Ml);
  } else {
    int m2 = mt - 2;
    mgemm_body(wkvI + (size_t)m2 * 128 * 64, 64,
               X + (size_t)b * 4194304 + (size_t)192 * HW + nt * 128,
               mod + b * 256 + 192,
               Yk + (size_t)b * 4194304 + (size_t)m2 * 128 * HW + nt * 128,
               64, threadIdx.x, Al, Bl, Ml);
  }
}

// ---------------------------------------------------------------------------
// depthwise 3x3, SAME zero pad, f32 out. One block per (channel, batch).
__global__ __launch_bounds__(256) void dwconv_kernel(
    const float* __restrict__ in, size_t in_bstride,
    const float* __restrict__ wdw,
    float* __restrict__ out, size_t out_bstride,
    float* __restrict__ ssq)
{
  int c = blockIdx.x;
  int b = blockIdx.y;
  int t = threadIdx.x;
  int r = t >> 5;
  int xq = t & 31;

  const float4* ip4 = (const float4*)(in + (size_t)b * in_bstride + ((size_t)c << 14));
  float4* op4 = (float4*)(out + (size_t)b * out_bstride + ((size_t)c << 14));
  const float* wp = wdw + c * 9;
  float w0 = wp[0], w1 = wp[1], w2 = wp[2], w3 = wp[3], w4 = wp[4],
        w5 = wp[5], w6 = wp[6], w7 = wp[7], w8 = wp[8];

  const float4 z4 = make_float4(0.f, 0.f, 0.f, 0.f);
  int y0 = r << 4;

  float4 a = (y0 > 0) ? ip4[((y0 - 1) << 5) + xq] : z4;
  float4 bb = ip4[(y0 << 5) + xq];

  float aL = __shfl_up(a.w, 1);  if (xq == 0)  aL = 0.f;
  float aR = __shfl_down(a.x, 1); if (xq == 31) aR = 0.f;
  float bL = __shfl_up(bb.w, 1); if (xq == 0)  bL = 0.f;
  float bR = __shfl_down(bb.x, 1); if (xq == 31) bR = 0.f;

  float ss = 0.f;
  #pragma unroll
  for (int i = 0; i < 16; ++i) {
    int y = y0 + i;
    int yc = (y + 1 < 128) ? (y + 1) : 127;
    float4 cc = ip4[(yc << 5) + xq];
    if (y + 1 >= 128) { cc.x = 0.f; cc.y = 0.f; cc.z = 0.f; cc.w = 0.f; }
    float cL = __shfl_up(cc.w, 1);  if (xq == 0)  cL = 0.f;
    float cR = __shfl_down(cc.x, 1); if (xq == 31) cR = 0.f;

    float4 o;
    o.x = w0 * aL  + w1 * a.x + w2 * a.y +
          w3 * bL  + w4 * bb.x + w5 * bb.y +
          w6 * cL  + w7 * cc.x + w8 * cc.y;
    o.y = w0 * a.x + w1 * a.y + w2 * a.z +
          w3 * bb.x + w4 * bb.y + w5 * bb.z +
          w6 * cc.x + w7 * cc.y + w8 * cc.z;
    o.z = w0 * a.y + w1 * a.z + w2 * a.w +
          w3 * bb.y + w4 * bb.z + w5 * bb.w +
          w6 * cc.y + w7 * cc.z + w8 * cc.w;
    o.w = w0 * a.z + w1 * a.w + w2 * aR +
          w3 * bb.z + w4 * bb.w + w5 * bR +
          w6 * cc.z + w7 * cc.w + w8 * cR;

    op4[(y << 5) + xq] = o;
    ss += o.x * o.x + o.y * o.y + o.z * o.z + o.w * o.w;

    a = bb; aL = bL; aR = bR;
    bb = cc; bL = cL; bR = cR;
  }

  if (ssq) {
    #pragma unroll
    for (int off = 32; off > 0; off >>= 1) ss += __shfl_down(ss, off);
    __shared__ float red[4];
    if ((t & 63) == 0) red[t >> 6] = ss;
    __syncthreads();
    if (t == 0) ssq[b * 256 + c] = red[0] + red[1] + red[2] + red[3];
  }
}

// ---------------------------------------------------------------------------
// MERGED gram + v-projection (independent ops, one dispatch).
// grid (16+128, 8, 4): x<16 -> gram chunk; x>=16 -> v-gemm (nt=x-16, mt=y<2).
// LDS union: gram uses 16 KB reduce buffer; v uses Al/Bl/Ml (21 KB).
__global__ __launch_bounds__(256, 2) void gram_v_kernel(
    const float* __restrict__ qdw, const float* __restrict__ kdw,
    float* __restrict__ S,
    const float* __restrict__ wv, const float* __restrict__ X,
    const float* __restrict__ mod, float* __restrict__ Yv)
{
  __shared__ __align__(16) unsigned char smem[21504];
  int t = threadIdx.x;
  int b = blockIdx.z;

  if (blockIdx.x >= 16) {
    // ---- v projection (K=64, c0=192)
    if (blockIdx.y >= 2) return;
    int nt = blockIdx.x - 16, mt = blockIdx.y;
    unsigned short* Al = (unsigned short*)smem;
    unsigned short* Bl = Al + 128 * 40;
    float* Ml = (float*)(smem + 20480);
    mgemm_body(wv + (size_t)mt * 128 * 64, 64,
               X + (size_t)b * 4194304 + (size_t)192 * HW + nt * 128,
               mod + b * 256 + 192,
               Yv + (size_t)b * 4194304 + (size_t)mt * 128 * HW + nt * 128,
               64, t, Al, Bl, Ml);
    return;
  }

  // ---- gram: S[b,h,c,d] += sum_p qdw[c,p]*kdw[d,p], hi/lo bf16 MFMA
  int chunk = blockIdx.x, h = blockIdx.y;
  int w = t >> 6, l = t & 63;
  int lm = l & 15;
  int lk8 = (l >> 4) * 8;

  const float* qh = qdw + (((size_t)b * 256 + h * 32) << 14);
  const float* kh = kdw + (((size_t)b * 256 + h * 32) << 14);
  const float* q0 = qh + ((size_t)lm << 14);
  const float* q1 = q0 + ((size_t)16 << 14);
  const float* k0 = kh + ((size_t)lm << 14);
  const float* k1 = k0 + ((size_t)16 << 14);

  int px0 = chunk * 1024 + w * 256 + lk8;

  f32x4 acc[2][2], accl[2][2];
  #pragma unroll
  for (int mi = 0; mi < 2; ++mi)
    #pragma unroll
    for (int nj = 0; nj < 2; ++nj) {
      acc[mi][nj] = {0.f, 0.f, 0.f, 0.f};
      accl[mi][nj] = {0.f, 0.f, 0.f, 0.f};
    }

  #pragma unroll 2
  for (int s = 0; s < 8; ++s) {
    int px = px0 + s * 32;
    float4 a0 = *(const float4*)(q0 + px);
    float4 a1 = *(const float4*)(q0 + px + 4);
    float4 a2 = *(const float4*)(q1 + px);
    float4 a3 = *(const float4*)(q1 + px + 4);
    float4 b0 = *(const float4*)(k0 + px);
    float4 b1 = *(const float4*)(k0 + px + 4);
    float4 b2 = *(const float4*)(k1 + px);
    float4 b3 = *(const float4*)(k1 + px + 4);

    bfrag qhF[2], qlF[2], khF[2], klF[2];
    cvt_hilo(a0, a1, qhF[0], qlF[0]);
    cvt_hilo(a2, a3, qhF[1], qlF[1]);
    cvt_hilo(b0, b1, khF[0], klF[0]);
    cvt_hilo(b2, b3, khF[1], klF[1]);

    #pragma unroll
    for (int mi = 0; mi < 2; ++mi)
      #pragma unroll
      for (int nj = 0; nj < 2; ++nj) {
        acc[mi][nj] = __builtin_amdgcn_mfma_f32_16x16x32_bf16(
            qhF[mi], khF[nj], acc[mi][nj], 0, 0, 0);
        accl[mi][nj] = __builtin_amdgcn_mfma_f32_16x16x32_bf16(
            qhF[mi], klF[nj], accl[mi][nj], 0, 0, 0);
        accl[mi][nj] = __builtin_amdgcn_mfma_f32_16x16x32_bf16(
            qlF[mi], khF[nj], accl[mi][nj], 0, 0, 0);
      }
  }

  float* red = (float*)smem;   // [4][1024]
  int orow = (l >> 4) * 4;
  #pragma unroll
  for (int mi = 0; mi < 2; ++mi)
    #pragma unroll
    for (int nj = 0; nj < 2; ++nj)
      #pragma unroll
      for (int r = 0; r < 4; ++r)
        red[w * 1024 + (mi * 16 + orow + r) * 32 + nj * 16 + lm] =
            acc[mi][nj][r] + accl[mi][nj][r];
  __syncthreads();
  float* Sp = S + (((size_t)b * 8 + h) << 10);
  for (int idx = t; idx < 1024; idx += 256)
    atomicAdd(&Sp[idx],
              red[idx] + red[1024 + idx] + red[2048 + idx] + red[3072 + idx]);
}

// ---------------------------------------------------------------------------
// MERGED softmax+mbuild and vdw-dwconv (bf16 out) in one dispatch.
// grid (512, 4): x<256 -> smb block (o=x, b=y); x>=256 -> dwconv channel
// c=x-256 of v_pre (b=y), writing RNE-bf16 (identical bits to the pack the
// out-gemm would have applied to f32 vdw).
__global__ __launch_bounds__(256) void smb_vdw_kernel(
    const float* __restrict__ S, const float* __restrict__ ssq,
    const float* __restrict__ ssk, const float* __restrict__ temp,
    const float* __restrict__ wproj, float* __restrict__ M,
    const float* __restrict__ vpre, const float* __restrict__ wvdw,
    unsigned short* __restrict__ vdw)
{
  int t = threadIdx.x;
  int b = blockIdx.y;

  if (blockIdx.x >= 256) {
    // ---- dwconv of v_pre channel c, bf16 output
    int c = blockIdx.x - 256;
    int r = t >> 5;
    int xq = t & 31;
    const float4* ip4 =
        (const float4*)(vpre + (size_t)b * 4194304 + ((size_t)c << 14));
    uint2* op2 = (uint2*)(vdw + (size_t)b * 4194304 + ((size_t)c << 14));
    const float* wp = wvdw + c * 9;
    float w0 = wp[0], w1 = wp[1], w2 = wp[2], w3 = wp[3], w4 = wp[4],
          w5 = wp[5], w6 = wp[6], w7 = wp[7], w8 = wp[8];
    const float4 z4 = make_float4(0.f, 0.f, 0.f, 0.f);
    int y0 = r << 4;
    float4 a = (y0 > 0) ? ip4[((y0 - 1) << 5) + xq] : z4;
    float4 bb = ip4[(y0 << 5) + xq];
    float aL = __shfl_up(a.w, 1);  if (xq == 0)  aL = 0.f;
    float aR = __shfl_down(a.x, 1); if (xq == 31) aR = 0.f;
    float bL = __shfl_up(bb.w, 1); if (xq == 0)  bL = 0.f;
    float bR = __shfl_down(bb.x, 1); if (xq == 31) bR = 0.f;
    #pragma unroll
    for (int i = 0; i < 16; ++i) {
      int y = y0 + i;
      int yc = (y + 1 < 128) ? (y + 1) : 127;
      float4 cc = ip4[(yc << 5) + xq];
      if (y + 1 >= 128) { cc.x = 0.f; cc.y = 0.f; cc.z = 0.f; cc.w = 0.f; }
      float cL = __shfl_up(cc.w, 1);  if (xq == 0)  cL = 0.f;
      float cR = __shfl_down(cc.x, 1); if (xq == 31) cR = 0.f;
      float4 o;
      o.x = w0 * aL  + w1 * a.x + w2 * a.y +
            w3 * bL  + w4 * bb.x + w5 * bb.y +
            w6 * cL  + w7 * cc.x + w8 * cc.y;
      o.y = w0 * a.x + w1 * a.y + w2 * a.z +
            w3 * bb.x + w4 * bb.y + w5 * bb.z +
            w6 * cc.x + w7 * cc.y + w8 * cc.z;
      o.z = w0 * a.y + w1 * a.z + w2 * a.w +
            w3 * bb.y + w4 * bb.z + w5 * bb.w +
            w6 * cc.y + w7 * cc.z + w8 * cc.w;
      o.w = w0 * a.z + w1 * a.w + w2 * aR +
            w3 * bb.z + w4 * bb.w + w5 * bR +
            w6 * cc.z + w7 * cc.w + w8 * cR;
      uint2 ob;
      ob.x = pack2bf(o.x, o.y);
      ob.y = pack2bf(o.z, o.w);
      op2[(y << 5) + xq] = ob;
      a = bb; aL = bL; aR = bR;
      bb = cc; bL = cL; bR = cR;
    }
    return;
  }

  // ---- softmax + mbuild
  int o = blockIdx.x;
  __shared__ float At[8 * 32 * 33];
  __shared__ float Iq[256], Ik[256], Wp[256];

  Iq[t] = 1.f / fmaxf(sqrtf(ssq[b * 256 + t]), 1e-12f);
  Ik[t] = 1.f / fmaxf(sqrtf(ssk[b * 256 + t]), 1e-12f);
  Wp[t] = wproj[o * 256 + t];
  __syncthreads();

  int h = t >> 5, c = t & 31;
  const float* row = S + (((size_t)b * 8 + h) << 10) + c * 32;
  float invq = Iq[h * 32 + c];
  float T = temp[h];
  float lg[32];
  float mx = -1e30f;
  #pragma unroll
  for (int d = 0; d < 32; ++d) {
    float v = row[d] * invq * Ik[h * 32 + d] * T;
    lg[d] = v;
    mx = fmaxf(mx, v);
  }
  float sum = 0.f;
  #pragma unroll
  for (int d = 0; d < 32; ++d) { float e = expf(lg[d] - mx); lg[d] = e; sum += e; }
  float inv = 1.f / sum;
  float* arow = &At[(h * 32 + c) * 33];
  #pragma unroll
  for (int d = 0; d < 32; ++d) arow[d] = lg[d] * inv;
  __syncthreads();

  int d2 = t & 31, h2 = t >> 5;
  float s = 0.f;
  #pragma unroll
  for (int cc = 0; cc < 32; ++cc)
    s += Wp[h2 * 32 + cc] * At[(h2 * 32 + cc) * 33 + d2];
  M[((size_t)b * 256 + o) * 256 + t] = s;
}

// ---------------------------------------------------------------------------
// out-gemm: out[b] = M[b] @ vdw[b], vdw already RNE-bf16 (ushort planes).
// Identical bits to the old f32-read + pack2bf path.
__global__ __launch_bounds__(256, 2) void mgemm_bx(
    const float* __restrict__ Mw, const unsigned short* __restrict__ Xb,
    float* __restrict__ out)
{
  __shared__ unsigned short Al[128 * 40];
  __shared__ unsigned short Bl[128 * 40];
  int b = blockIdx.z, mt = blockIdx.y, nt = blockIdx.x;
  const float* Wt = Mw + (size_t)b * 65536 + (size_t)mt * 128 * 256;
  const unsigned short* Xt = Xb + (size_t)b * 4194304 + nt * 128;
  float* Yt = out + (size_t)b * 4194304 + (size_t)mt * 128 * HW + nt * 128;
  int t = threadIdx.x;
  const int K = 256;

  int w = t >> 6, l = t & 63;
  int wm = (w >> 1) * 64, wn = (w & 1) * 64;
  int lm = l & 15, lk = (l >> 4) * 8;
  int am = t >> 1, ako = (t & 1) * 16;
  int bn = t & 127, bo = (t >> 7) * 8;

  f32x4 acc[4][4];
  #pragma unroll
  for (int fi = 0; fi < 4; ++fi)
    #pragma unroll
    for (int fj = 0; fj < 4; ++fj) acc[fi][fj] = {0.f, 0.f, 0.f, 0.f};

  unsigned short xrA[16], xrB[16];
  float4 wv0, wv1, wv2, wv3;

  auto load_x = [&](unsigned short* xr, int k0) {
    #pragma unroll
    for (int i = 0; i < 2; ++i) {
      int kb = k0 + bo + i * 16;
      #pragma unroll
      for (int r = 0; r < 8; ++r)
        xr[i * 8 + r] = Xt[(size_t)(kb + r) * HW + bn];
    }
  };
  auto load_w = [&](int k0) {
    const float* wsrc = Wt + (size_t)am * 256 + k0 + ako;
    wv0 = *(const float4*)(wsrc);
    wv1 = *(const float4*)(wsrc + 4);
    wv2 = *(const float4*)(wsrc + 8);
    wv3 = *(const float4*)(wsrc + 12);
  };
  auto pack_a = [&]() {
    uint4 aw0, aw1;
    aw0.x = pack2bf(wv0.x, wv0.y); aw0.y = pack2bf(wv0.z, wv0.w);
    aw0.z = pack2bf(wv1.x, wv1.y); aw0.w = pack2bf(wv1.z, wv1.w);
    aw1.x = pack2bf(wv2.x, wv2.y); aw1.y = pack2bf(wv2.z, wv2.w);
    aw1.z = pack2bf(wv3.x, wv3.y); aw1.w = pack2bf(wv3.z, wv3.w);
    *(uint4*)&Al[am * 40 + ako] = aw0;
    *(uint4*)&Al[am * 40 + ako + 8] = aw1;
  };
  auto pack_b = [&](const unsigned short* xr) {
    #pragma unroll
    for (int i = 0; i < 2; ++i) {
      uint4 bw;
      bw.x = (uint)xr[i * 8 + 0] | ((uint)xr[i * 8 + 1] << 16);
      bw.y = (uint)xr[i * 8 + 2] | ((uint)xr[i * 8 + 3] << 16);
      bw.z = (uint)xr[i * 8 + 4] | ((uint)xr[i * 8 + 5] << 16);
      bw.w = (uint)xr[i * 8 + 6] | ((uint)xr[i * 8 + 7] << 16);
      *(uint4*)&Bl[bn * 40 + bo + i * 16] = bw;
    }
  };
  auto mfma_step = [&]() {
    bfrag af[4], bfr[4];
    #pragma unroll
    for (int fj = 0; fj < 4; ++fj) {
      FragCvt cv;
      cv.u = *(const uint4*)&Al[(wm + fj * 16 + lm) * 40 + lk];
      af[fj] = cv.v;
    }
    #pragma unroll
    for (int fi = 0; fi < 4; ++fi) {
      FragCvt cv;
      cv.u = *(const uint4*)&Bl[(wn + fi * 16 + lm) * 40 + lk];
      bfr[fi] = cv.v;
    }
    #pragma unroll
    for (int fi = 0; fi < 4; ++fi)
      #pragma unroll
      for (int fj = 0; fj < 4; ++fj)
        acc[fi][fj] = __builtin_amdgcn_mfma_f32_16x16x32_bf16(
            bfr[fi], af[fj], acc[fi][fj], 0, 0, 0);
  };

  load_x(xrA, 0);
  load_x(xrB, 32);
  load_w(0);

  for (int k0 = 0; k0 < K; k0 += 64) {
    LDS_BARRIER();
    pack_a();
    if (k0 + 32 < K) load_w(k0 + 32);
    pack_b(xrA);
    if (k0 + 64 < K) load_x(xrA, k0 + 64);
    LDS_BARRIER();
    mfma_step();

    LDS_BARRIER();
    pack_a();
    if (k0 + 64 < K) load_w(k0 + 64);
    pack_b(xrB);
    if (k0 + 96 < K) load_x(xrB, k0 + 96);
    LDS_BARRIER();
    mfma_step();
  }

  int ph = (l >> 4) * 4;
  #pragma unroll
  for (int fi = 0; fi < 4; ++fi)
    #pragma unroll
    for (int fj = 0; fj < 4; ++fj)
      *(f32x4*)&Yt[(size_t)(wm + fj * 16 + lm) * HW + wn + fi * 16 + ph] =
          acc[fi][fj];
}

// ---------------------------------------------------------------------------
extern "C" void kernel_launch(void* const* d_in, const int* in_sizes, int n_in,
                              void* d_out, int out_size, void* d_ws, size_t ws_size,
                              hipStream_t stream)
{
  const float* x      = (const float*)d_in[0];
  const float* k_v    = (const float*)d_in[1];
  const float* temp   = (const float*)d_in[2];
  const float* w_kR   = (const float*)d_in[3];
  const float* w_kI   = (const float*)d_in[4];
  const float* w_qR   = (const float*)d_in[5];
  const float* w_qdw  = (const float*)d_in[6];
  const float* w_kvI  = (const float*)d_in[7];
  const float* w_kvdw = (const float*)d_in[8];
  const float* w_proj = (const float*)d_in[9];
  float* out = (float*)d_out;

  float* ws   = (float*)d_ws;
  float* bufA = ws;                 // 64 MB
  float* bufB = ws + 16777216;      // 64 MB
  float* bufC = ws + 33554432;      // 64 MB (reused as bf16 vdw at the end)
  float* sm   = ws + 50331648;      // small region at 192 MB
  float* mod  = sm;                 // 1024
  float* ssq  = sm + 1024;          // 1024 (q norms^2, plain store)
  float* ssk  = sm + 2048;          // 1024 (k norms^2, plain store)
  float* S    = sm + 3072;          // 32768 (Gram -> attn via softmax_mbuild)
  float* M    = sm + 3072 + 32768;  // 262144 (fused attn+proj matrix)

  // 1. mod + S-zeroing
  mod_kernel<<<dim3(4), dim3(256), 0, stream>>>(k_v, w_kR, w_kI, mod, S);

  // 2. q_pre -> bufA ; k_pre -> bufB
  mgemm_qk<<<dim3(128, 4, 4), dim3(256), 0, stream>>>(
      w_qR, w_kvI, x, mod, bufA, bufB);

  // 3. kdw -> bufC (+ k norms)
  dwconv_kernel<<<dim3(256, 4), dim3(256), 0, stream>>>(
      bufB, 4194304, w_kvdw, bufC, 4194304, ssk);

  // 4. qdw -> bufB (+ q norms; k_pre dead)
  dwconv_kernel<<<dim3(256, 4), dim3(256), 0, stream>>>(
      bufA, 4194304, w_qdw, bufB, 4194304, ssq);

  // 5. gram(S) || v_pre -> bufA   (q_pre dead after step 4)
  gram_v_kernel<<<dim3(144, 8, 4), dim3(256), 0, stream>>>(
      bufB, bufC, S, w_kvI + 256 * 64, x, mod, bufA);

  // 6. softmax+mbuild(M) || vdw(bf16) -> bufC  (kdw dead after gram)
  smb_vdw_kernel<<<dim3(512, 4), dim3(256), 0, stream>>>(
      S, ssq, ssk, temp, w_proj, M,
      bufA, w_kvdw + 256 * 9, (unsigned short*)bufC);

  // 7. out = M[b] @ vdw[b] (bf16 vdw)
  mgemm_bx<<<dim3(128, 2, 4), dim3(256), 0, stream>>>(
      M, (const unsigned short*)bufC, out);
}

// Round 11
// 302.549 us; speedup vs baseline: 1.8543x; 1.0055x over previous
//
#include <hip/hip_runtime.h>
#include <math.h>

#define HW 16384

typedef unsigned int uint;
typedef short bfrag __attribute__((ext_vector_type(8)));   // 8 bf16 (4 VGPRs)
typedef float f32x4 __attribute__((ext_vector_type(4)));   // 4 fp32 acc

union FragCvt { uint4 u; bfrag v; };

// round-to-nearest-even f32 -> bf16, pack two into a dword
__device__ inline uint pack2bf(float a, float b) {
  uint ua = __builtin_bit_cast(uint, a);
  uint ub = __builtin_bit_cast(uint, b);
  ua = (ua + 0x7FFFu + ((ua >> 16) & 1u)) >> 16;
  ub = (ub + 0x7FFFu + ((ub >> 16) & 1u)) & 0xFFFF0000u;
  return ua | ub;
}

// split 8 f32 into hi-bf16 frag and lo-bf16 frag (hi = RNE(x), lo = RNE(x-hi))
__device__ inline void cvt_hilo(float4 a, float4 b, bfrag& hi, bfrag& lo) {
  float v0[8] = {a.x, a.y, a.z, a.w, b.x, b.y, b.z, b.w};
  uint hv[4], lv[4];
  #pragma unroll
  for (int i = 0; i < 4; ++i) {
    float x0 = v0[2 * i], x1 = v0[2 * i + 1];
    uint h = pack2bf(x0, x1);
    float h0 = __builtin_bit_cast(float, h << 16);
    float h1 = __builtin_bit_cast(float, h & 0xFFFF0000u);
    hv[i] = h;
    lv[i] = pack2bf(x0 - h0, x1 - h1);
  }
  FragCvt ch, cl;
  ch.u = make_uint4(hv[0], hv[1], hv[2], hv[3]);
  cl.u = make_uint4(lv[0], lv[1], lv[2], lv[3]);
  hi = ch.v;
  lo = cl.v;
}

// LDS-only barrier: waits for this wave's LDS ops (lgkmcnt) but lets global
// loads (vmcnt) stay in flight across the barrier.
#define LDS_BARRIER() do { \
  asm volatile("s_waitcnt lgkmcnt(0)" ::: "memory"); \
  __builtin_amdgcn_s_barrier(); \
} while (0)

// ---------------------------------------------------------------------------
// mod[b,c] = 1 + (k_v @ w.T); also zeroes S (replaces the memset dispatch).
__global__ __launch_bounds__(256) void mod_kernel(
    const float* __restrict__ kv, const float* __restrict__ wkR,
    const float* __restrict__ wkI, float* __restrict__ mod,
    float* __restrict__ S)
{
  int b = blockIdx.x;
  int c = threadIdx.x;
  float4 z4 = make_float4(0.f, 0.f, 0.f, 0.f);
  float4* sp = (float4*)(S + (((size_t)b * 256 + c) << 5));
  #pragma unroll
  for (int i = 0; i < 8; ++i) sp[i] = z4;

  const float* kvb = kv + b * 256;
  float s = 0.f;
  if (c < 192) {
    const float* wr = wkR + c * 192;
    for (int j = 0; j < 192; ++j) s += kvb[j] * wr[j];
  } else {
    const float* wi = wkI + (c - 192) * 64;
    for (int j = 0; j < 64; ++j) s += kvb[192 + j] * wi[j];
  }
  mod[b * 256 + c] = 1.f + s;
}

// ---------------------------------------------------------------------------
// GEMM body (R6-proven): Y[128 x 128px] = W[128,K] @ (X[k,:] * mod[k]).
// 4 waves 2x2, 4x4 frags 16x16x32, f32 accum. X depth-2 prefetch; W depth-1;
// LDS_BARRIER keeps global loads in flight across barriers.
__device__ __forceinline__ void mgemm_body(
    const float* __restrict__ Wt, int ldW,
    const float* __restrict__ Xt,
    const float* __restrict__ modc,
    float* __restrict__ Yt,
    int K, int t, unsigned short* Al, unsigned short* Bl, float* Ml)
{
  int w = t >> 6, l = t & 63;
  int wm = (w >> 1) * 64, wn = (w & 1) * 64;
  int lm = l & 15, lk = (l >> 4) * 8;

  int am = t >> 1, ako = (t & 1) * 16;
  int bn = t & 127, bo = (t >> 7) * 8;

  Ml[t] = (modc && t < K) ? modc[t] : 1.f;

  f32x4 acc[4][4];
  #pragma unroll
  for (int fi = 0; fi < 4; ++fi)
    #pragma unroll
    for (int fj = 0; fj < 4; ++fj) acc[fi][fj] = {0.f, 0.f, 0.f, 0.f};

  float xrA[16], xrB[16];
  float4 wv0, wv1, wv2, wv3;

  auto load_x = [&](float* xr, int k0) {
    #pragma unroll
    for (int i = 0; i < 2; ++i) {
      int kb = k0 + bo + i * 16;
      #pragma unroll
      for (int r = 0; r < 8; ++r)
        xr[i * 8 + r] = Xt[(size_t)(kb + r) * HW + bn];
    }
  };
  auto load_w = [&](int k0) {
    const float* wsrc = Wt + (size_t)am * ldW + k0 + ako;
    wv0 = *(const float4*)(wsrc);
    wv1 = *(const float4*)(wsrc + 4);
    wv2 = *(const float4*)(wsrc + 8);
    wv3 = *(const float4*)(wsrc + 12);
  };
  auto pack_a = [&]() {
    uint4 aw0, aw1;
    aw0.x = pack2bf(wv0.x, wv0.y); aw0.y = pack2bf(wv0.z, wv0.w);
    aw0.z = pack2bf(wv1.x, wv1.y); aw0.w = pack2bf(wv1.z, wv1.w);
    aw1.x = pack2bf(wv2.x, wv2.y); aw1.y = pack2bf(wv2.z, wv2.w);
    aw1.z = pack2bf(wv3.x, wv3.y); aw1.w = pack2bf(wv3.z, wv3.w);
    *(uint4*)&Al[am * 40 + ako] = aw0;
    *(uint4*)&Al[am * 40 + ako + 8] = aw1;
  };
  auto pack_b = [&](const float* xr, int k0) {
    #pragma unroll
    for (int i = 0; i < 2; ++i) {
      float4 m0 = *(const float4*)&Ml[k0 + bo + i * 16];
      float4 m1 = *(const float4*)&Ml[k0 + bo + i * 16 + 4];
      uint4 bw;
      bw.x = pack2bf(xr[i * 8 + 0] * m0.x, xr[i * 8 + 1] * m0.y);
      bw.y = pack2bf(xr[i * 8 + 2] * m0.z, xr[i * 8 + 3] * m0.w);
      bw.z = pack2bf(xr[i * 8 + 4] * m1.x, xr[i * 8 + 5] * m1.y);
      bw.w = pack2bf(xr[i * 8 + 6] * m1.z, xr[i * 8 + 7] * m1.w);
      *(uint4*)&Bl[bn * 40 + bo + i * 16] = bw;
    }
  };
  auto mfma_step = [&]() {
    bfrag af[4], bfr[4];
    #pragma unroll
    for (int fj = 0; fj < 4; ++fj) {
      FragCvt cv;
      cv.u = *(const uint4*)&Al[(wm + fj * 16 + lm) * 40 + lk];
      af[fj] = cv.v;
    }
    #pragma unroll
    for (int fi = 0; fi < 4; ++fi) {
      FragCvt cv;
      cv.u = *(const uint4*)&Bl[(wn + fi * 16 + lm) * 40 + lk];
      bfr[fi] = cv.v;
    }
    #pragma unroll
    for (int fi = 0; fi < 4; ++fi)
      #pragma unroll
      for (int fj = 0; fj < 4; ++fj)
        acc[fi][fj] = __builtin_amdgcn_mfma_f32_16x16x32_bf16(
            bfr[fi], af[fj], acc[fi][fj], 0, 0, 0);
  };

  load_x(xrA, 0);
  load_x(xrB, 32);
  load_w(0);

  for (int k0 = 0; k0 < K; k0 += 64) {
    LDS_BARRIER();
    pack_a();
    if (k0 + 32 < K) load_w(k0 + 32);
    pack_b(xrA, k0);
    if (k0 + 64 < K) load_x(xrA, k0 + 64);
    LDS_BARRIER();
    mfma_step();

    LDS_BARRIER();
    pack_a();
    if (k0 + 64 < K) load_w(k0 + 64);
    pack_b(xrB, k0 + 32);
    if (k0 + 96 < K) load_x(xrB, k0 + 96);
    LDS_BARRIER();
    mfma_step();
  }

  int ph = (l >> 4) * 4;
  #pragma unroll
  for (int fi = 0; fi < 4; ++fi)
    #pragma unroll
    for (int fj = 0; fj < 4; ++fj)
      *(f32x4*)&Yt[(size_t)(wm + fj * 16 + lm) * HW + wn + fi * 16 + ph] =
          acc[fi][fj];
}

// merged q (mt 0-1, K=192, c0=0) + k (mt 2-3) + v (mt 4-5) projections
__global__ __launch_bounds__(256, 2) void mgemm_qkv(
    const float* __restrict__ wqR, const float* __restrict__ wkvI,
    const float* __restrict__ X, const float* __restrict__ mod,
    float* __restrict__ Yq, float* __restrict__ Yk, float* __restrict__ Yv)
{
  __shared__ unsigned short Al[128 * 40];
  __shared__ unsigned short Bl[128 * 40];
  __shared__ float Ml[256];
  int b = blockIdx.z, mt = blockIdx.y, nt = blockIdx.x;
  if (mt < 2) {
    mgemm_body(wqR + (size_t)mt * 128 * 192, 192,
               X + (size_t)b * 4194304 + nt * 128,
               mod + b * 256,
               Yq + (size_t)b * 4194304 + (size_t)mt * 128 * HW + nt * 128,
               192, threadIdx.x, Al, Bl, Ml);
  } else if (mt < 4) {
    int m2 = mt - 2;
    mgemm_body(wkvI + (size_t)m2 * 128 * 64, 64,
               X + (size_t)b * 4194304 + (size_t)192 * HW + nt * 128,
               mod + b * 256 + 192,
               Yk + (size_t)b * 4194304 + (size_t)m2 * 128 * HW + nt * 128,
               64, threadIdx.x, Al, Bl, Ml);
  } else {
    int m2 = mt - 4;
    mgemm_body(wkvI + (size_t)(256 + m2 * 128) * 64, 64,
               X + (size_t)b * 4194304 + (size_t)192 * HW + nt * 128,
               mod + b * 256 + 192,
               Yv + (size_t)b * 4194304 + (size_t)m2 * 128 * HW + nt * 128,
               64, threadIdx.x, Al, Bl, Ml);
  }
}

// ---------------------------------------------------------------------------
// MERGED in-place depthwise 3x3 on q_pre, k_pre, v_pre (one dispatch).
// grid (768, 4): which = x>>8 -> 0: kdw on kbuf (+ssk), 1: qdw on qbuf (+ssq),
// 2: vdw on vbuf writing RNE-bf16 into the SAME plane byte-range.
// In-place safety: phase 1 computes all 16 rows into registers (reads rows
// y0-1..y0+16), __syncthreads (every wave's halo reads complete), phase 2
// stores. Each plane is owned by exactly one block.
__global__ __launch_bounds__(256) void dw3_kernel(
    float* __restrict__ qbuf, float* __restrict__ kbuf, float* __restrict__ vbuf,
    const float* __restrict__ wqdw, const float* __restrict__ wkvdw,
    float* __restrict__ ssq, float* __restrict__ ssk)
{
  int g = blockIdx.x;
  int b = blockIdx.y;
  int c = g & 255;
  int which = g >> 8;   // 0: kdw, 1: qdw, 2: vdw->bf16

  float* buf = (which == 0) ? kbuf : ((which == 1) ? qbuf : vbuf);
  const float* wp = (which == 1) ? (wqdw + c * 9)
                  : (which == 0) ? (wkvdw + c * 9)
                                 : (wkvdw + (256 + c) * 9);

  int t = threadIdx.x;
  int r = t >> 5;
  int xq = t & 31;

  float* plane = buf + (size_t)b * 4194304 + ((size_t)c << 14);
  const float4* ip4 = (const float4*)plane;
  float w0 = wp[0], w1 = wp[1], w2 = wp[2], w3 = wp[3], w4 = wp[4],
        w5 = wp[5], w6 = wp[6], w7 = wp[7], w8 = wp[8];

  const float4 z4 = make_float4(0.f, 0.f, 0.f, 0.f);
  int y0 = r << 4;

  float4 a = (y0 > 0) ? ip4[((y0 - 1) << 5) + xq] : z4;
  float4 bb = ip4[(y0 << 5) + xq];

  float aL = __shfl_up(a.w, 1);  if (xq == 0)  aL = 0.f;
  float aR = __shfl_down(a.x, 1); if (xq == 31) aR = 0.f;
  float bL = __shfl_up(bb.w, 1); if (xq == 0)  bL = 0.f;
  float bR = __shfl_down(bb.x, 1); if (xq == 31) bR = 0.f;

  float ss = 0.f;
  float4 ores[16];
  #pragma unroll
  for (int i = 0; i < 16; ++i) {
    int y = y0 + i;
    int yc = (y + 1 < 128) ? (y + 1) : 127;
    float4 cc = ip4[(yc << 5) + xq];
    if (y + 1 >= 128) { cc.x = 0.f; cc.y = 0.f; cc.z = 0.f; cc.w = 0.f; }
    float cL = __shfl_up(cc.w, 1);  if (xq == 0)  cL = 0.f;
    float cR = __shfl_down(cc.x, 1); if (xq == 31) cR = 0.f;

    float4 o;
    o.x = w0 * aL  + w1 * a.x + w2 * a.y +
          w3 * bL  + w4 * bb.x + w5 * bb.y +
          w6 * cL  + w7 * cc.x + w8 * cc.y;
    o.y = w0 * a.x + w1 * a.y + w2 * a.z +
          w3 * bb.x + w4 * bb.y + w5 * bb.z +
          w6 * cc.x + w7 * cc.y + w8 * cc.z;
    o.z = w0 * a.y + w1 * a.z + w2 * a.w +
          w3 * bb.y + w4 * bb.z + w5 * bb.w +
          w6 * cc.y + w7 * cc.z + w8 * cc.w;
    o.w = w0 * a.z + w1 * a.w + w2 * aR +
          w3 * bb.z + w4 * bb.w + w5 * bR +
          w6 * cc.z + w7 * cc.w + w8 * cR;

    ores[i] = o;
    ss += o.x * o.x + o.y * o.y + o.z * o.z + o.w * o.w;

    a = bb; aL = bL; aR = bR;
    bb = cc; bL = cL; bR = cR;
  }

  __syncthreads();   // all halo reads of this plane complete before writes

  if (which < 2) {
    float4* op4 = (float4*)plane;
    #pragma unroll
    for (int i = 0; i < 16; ++i) op4[((y0 + i) << 5) + xq] = ores[i];
  } else {
    uint2* op2 = (uint2*)plane;   // bf16 plane in same byte-range (half used)
    #pragma unroll
    for (int i = 0; i < 16; ++i) {
      uint2 ob;
      ob.x = pack2bf(ores[i].x, ores[i].y);
      ob.y = pack2bf(ores[i].z, ores[i].w);
      op2[((y0 + i) << 5) + xq] = ob;
    }
  }

  if (which < 2) {
    float* ssp = (which == 0) ? ssk : ssq;
    #pragma unroll
    for (int off = 32; off > 0; off >>= 1) ss += __shfl_down(ss, off);
    __shared__ float red[4];
    if ((t & 63) == 0) red[t >> 6] = ss;
    __syncthreads();
    if (t == 0) ssp[b * 256 + c] = red[0] + red[1] + red[2] + red[3];
  }
}

// ---------------------------------------------------------------------------
// S[b,h,c,d] += sum_p qdw[b,h*32+c,p] * kdw[b,h*32+d,p]  (unnormalized Gram)
// MFMA split-K, hi/lo bf16 decomposition; no LDS staging in the main loop.
__global__ __launch_bounds__(256) void gram_kernel(
    const float* __restrict__ qdw, const float* __restrict__ kdw,
    float* __restrict__ S)
{
  int chunk = blockIdx.x, h = blockIdx.y, b = blockIdx.z;
  int t = threadIdx.x;
  int w = t >> 6, l = t & 63;
  int lm = l & 15;
  int lk8 = (l >> 4) * 8;

  const float* qh = qdw + (((size_t)b * 256 + h * 32) << 14);
  const float* kh = kdw + (((size_t)b * 256 + h * 32) << 14);
  const float* q0 = qh + ((size_t)lm << 14);
  const float* q1 = q0 + ((size_t)16 << 14);
  const float* k0 = kh + ((size_t)lm << 14);
  const float* k1 = k0 + ((size_t)16 << 14);

  int px0 = chunk * 1024 + w * 256 + lk8;

  f32x4 acc[2][2], accl[2][2];
  #pragma unroll
  for (int mi = 0; mi < 2; ++mi)
    #pragma unroll
    for (int nj = 0; nj < 2; ++nj) {
      acc[mi][nj] = {0.f, 0.f, 0.f, 0.f};
      accl[mi][nj] = {0.f, 0.f, 0.f, 0.f};
    }

  #pragma unroll 2
  for (int s = 0; s < 8; ++s) {
    int px = px0 + s * 32;
    float4 a0 = *(const float4*)(q0 + px);
    float4 a1 = *(const float4*)(q0 + px + 4);
    float4 a2 = *(const float4*)(q1 + px);
    float4 a3 = *(const float4*)(q1 + px + 4);
    float4 b0 = *(const float4*)(k0 + px);
    float4 b1 = *(const float4*)(k0 + px + 4);
    float4 b2 = *(const float4*)(k1 + px);
    float4 b3 = *(const float4*)(k1 + px + 4);

    bfrag qhF[2], qlF[2], khF[2], klF[2];
    cvt_hilo(a0, a1, qhF[0], qlF[0]);
    cvt_hilo(a2, a3, qhF[1], qlF[1]);
    cvt_hilo(b0, b1, khF[0], klF[0]);
    cvt_hilo(b2, b3, khF[1], klF[1]);

    #pragma unroll
    for (int mi = 0; mi < 2; ++mi)
      #pragma unroll
      for (int nj = 0; nj < 2; ++nj) {
        acc[mi][nj] = __builtin_amdgcn_mfma_f32_16x16x32_bf16(
            qhF[mi], khF[nj], acc[mi][nj], 0, 0, 0);
        accl[mi][nj] = __builtin_amdgcn_mfma_f32_16x16x32_bf16(
            qhF[mi], klF[nj], accl[mi][nj], 0, 0, 0);
        accl[mi][nj] = __builtin_amdgcn_mfma_f32_16x16x32_bf16(
            qlF[mi], khF[nj], accl[mi][nj], 0, 0, 0);
      }
  }

  __shared__ float red[4][1024];
  int orow = (l >> 4) * 4;
  #pragma unroll
  for (int mi = 0; mi < 2; ++mi)
    #pragma unroll
    for (int nj = 0; nj < 2; ++nj)
      #pragma unroll
      for (int r = 0; r < 4; ++r)
        red[w][(mi * 16 + orow + r) * 32 + nj * 16 + lm] =
            acc[mi][nj][r] + accl[mi][nj][r];
  __syncthreads();
  float* Sp = S + (((size_t)b * 8 + h) << 10);
  for (int idx = t; idx < 1024; idx += 256)
    atomicAdd(&Sp[idx], red[0][idx] + red[1][idx] + red[2][idx] + red[3][idx]);
}

// ---------------------------------------------------------------------------
// FUSED softmax + mbuild: block (o,b) softmaxes S[b] into LDS then computes
// M[b][o][h*32+d] = sum_c w_proj[o][h*32+c] * attn[b,h,c,d].
__global__ __launch_bounds__(256) void smb_kernel(
    const float* __restrict__ S, const float* __restrict__ ssq,
    const float* __restrict__ ssk, const float* __restrict__ temp,
    const float* __restrict__ wproj, float* __restrict__ M)
{
  int o = blockIdx.x, b = blockIdx.y;
  int t = threadIdx.x;
  __shared__ float At[8 * 32 * 33];
  __shared__ float Iq[256], Ik[256], Wp[256];

  Iq[t] = 1.f / fmaxf(sqrtf(ssq[b * 256 + t]), 1e-12f);
  Ik[t] = 1.f / fmaxf(sqrtf(ssk[b * 256 + t]), 1e-12f);
  Wp[t] = wproj[o * 256 + t];
  __syncthreads();

  int h = t >> 5, c = t & 31;
  const float* row = S + (((size_t)b * 8 + h) << 10) + c * 32;
  float invq = Iq[h * 32 + c];
  float T = temp[h];
  float lg[32];
  float mx = -1e30f;
  #pragma unroll
  for (int d = 0; d < 32; ++d) {
    float v = row[d] * invq * Ik[h * 32 + d] * T;
    lg[d] = v;
    mx = fmaxf(mx, v);
  }
  float sum = 0.f;
  #pragma unroll
  for (int d = 0; d < 32; ++d) { float e = expf(lg[d] - mx); lg[d] = e; sum += e; }
  float inv = 1.f / sum;
  float* arow = &At[(h * 32 + c) * 33];
  #pragma unroll
  for (int d = 0; d < 32; ++d) arow[d] = lg[d] * inv;
  __syncthreads();

  int d2 = t & 31, h2 = t >> 5;
  float s = 0.f;
  #pragma unroll
  for (int cc = 0; cc < 32; ++cc)
    s += Wp[h2 * 32 + cc] * At[(h2 * 32 + cc) * 33 + d2];
  M[((size_t)b * 256 + o) * 256 + t] = s;
}

// ---------------------------------------------------------------------------
// out-gemm: out[b] = M[b] @ vdw[b], vdw stored as RNE-bf16 inside the f32
// plane byte-range: k-row stride 32768 ushorts, batch stride 8388608 ushorts.
__global__ __launch_bounds__(256, 2) void mgemm_bx(
    const float* __restrict__ Mw, const unsigned short* __restrict__ Xb,
    float* __restrict__ out)
{
  __shared__ unsigned short Al[128 * 40];
  __shared__ unsigned short Bl[128 * 40];
  int b = blockIdx.z, mt = blockIdx.y, nt = blockIdx.x;
  const float* Wt = Mw + (size_t)b * 65536 + (size_t)mt * 128 * 256;
  const unsigned short* Xt = Xb + (size_t)b * 8388608 + nt * 128;
  float* Yt = out + (size_t)b * 4194304 + (size_t)mt * 128 * HW + nt * 128;
  int t = threadIdx.x;
  const int K = 256;

  int w = t >> 6, l = t & 63;
  int wm = (w >> 1) * 64, wn = (w & 1) * 64;
  int lm = l & 15, lk = (l >> 4) * 8;
  int am = t >> 1, ako = (t & 1) * 16;
  int bn = t & 127, bo = (t >> 7) * 8;

  f32x4 acc[4][4];
  #pragma unroll
  for (int fi = 0; fi < 4; ++fi)
    #pragma unroll
    for (int fj = 0; fj < 4; ++fj) acc[fi][fj] = {0.f, 0.f, 0.f, 0.f};

  unsigned short xrA[16], xrB[16];
  float4 wv0, wv1, wv2, wv3;

  auto load_x = [&](unsigned short* xr, int k0) {
    #pragma unroll
    for (int i = 0; i < 2; ++i) {
      int kb = k0 + bo + i * 16;
      #pragma unroll
      for (int r = 0; r < 8; ++r)
        xr[i * 8 + r] = Xt[(size_t)(kb + r) * 32768 + bn];
    }
  };
  auto load_w = [&](int k0) {
    const float* wsrc = Wt + (size_t)am * 256 + k0 + ako;
    wv0 = *(const float4*)(wsrc);
    wv1 = *(const float4*)(wsrc + 4);
    wv2 = *(const float4*)(wsrc + 8);
    wv3 = *(const float4*)(wsrc + 12);
  };
  auto pack_a = [&]() {
    uint4 aw0, aw1;
    aw0.x = pack2bf(wv0.x, wv0.y); aw0.y = pack2bf(wv0.z, wv0.w);
    aw0.z = pack2bf(wv1.x, wv1.y); aw0.w = pack2bf(wv1.z, wv1.w);
    aw1.x = pack2bf(wv2.x, wv2.y); aw1.y = pack2bf(wv2.z, wv2.w);
    aw1.z = pack2bf(wv3.x, wv3.y); aw1.w = pack2bf(wv3.z, wv3.w);
    *(uint4*)&Al[am * 40 + ako] = aw0;
    *(uint4*)&Al[am * 40 + ako + 8] = aw1;
  };
  auto pack_b = [&](const unsigned short* xr) {
    #pragma unroll
    for (int i = 0; i < 2; ++i) {
      uint4 bw;
      bw.x = (uint)xr[i * 8 + 0] | ((uint)xr[i * 8 + 1] << 16);
      bw.y = (uint)xr[i * 8 + 2] | ((uint)xr[i * 8 + 3] << 16);
      bw.z = (uint)xr[i * 8 + 4] | ((uint)xr[i * 8 + 5] << 16);
      bw.w = (uint)xr[i * 8 + 6] | ((uint)xr[i * 8 + 7] << 16);
      *(uint4*)&Bl[bn * 40 + bo + i * 16] = bw;
    }
  };
  auto mfma_step = [&]() {
    bfrag af[4], bfr[4];
    #pragma unroll
    for (int fj = 0; fj < 4; ++fj) {
      FragCvt cv;
      cv.u = *(const uint4*)&Al[(wm + fj * 16 + lm) * 40 + lk];
      af[fj] = cv.v;
    }
    #pragma unroll
    for (int fi = 0; fi < 4; ++fi) {
      FragCvt cv;
      cv.u = *(const uint4*)&Bl[(wn + fi * 16 + lm) * 40 + lk];
      bfr[fi] = cv.v;
    }
    #pragma unroll
    for (int fi = 0; fi < 4; ++fi)
      #pragma unroll
      for (int fj = 0; fj < 4; ++fj)
        acc[fi][fj] = __builtin_amdgcn_mfma_f32_16x16x32_bf16(
            bfr[fi], af[fj], acc[fi][fj], 0, 0, 0);
  };

  load_x(xrA, 0);
  load_x(xrB, 32);
  load_w(0);

  for (int k0 = 0; k0 < K; k0 += 64) {
    LDS_BARRIER();
    pack_a();
    if (k0 + 32 < K) load_w(k0 + 32);
    pack_b(xrA);
    if (k0 + 64 < K) load_x(xrA, k0 + 64);
    LDS_BARRIER();
    mfma_step();

    LDS_BARRIER();
    pack_a();
    if (k0 + 64 < K) load_w(k0 + 64);
    pack_b(xrB);
    if (k0 + 96 < K) load_x(xrB, k0 + 96);
    LDS_BARRIER();
    mfma_step();
  }

  int ph = (l >> 4) * 4;
  #pragma unroll
  for (int fi = 0; fi < 4; ++fi)
    #pragma unroll
    for (int fj = 0; fj < 4; ++fj)
      *(f32x4*)&Yt[(size_t)(wm + fj * 16 + lm) * HW + wn + fi * 16 + ph] =
          acc[fi][fj];
}

// ---------------------------------------------------------------------------
extern "C" void kernel_launch(void* const* d_in, const int* in_sizes, int n_in,
                              void* d_out, int out_size, void* d_ws, size_t ws_size,
                              hipStream_t stream)
{
  const float* x      = (const float*)d_in[0];
  const float* k_v    = (const float*)d_in[1];
  const float* temp   = (const float*)d_in[2];
  const float* w_kR   = (const float*)d_in[3];
  const float* w_kI   = (const float*)d_in[4];
  const float* w_qR   = (const float*)d_in[5];
  const float* w_qdw  = (const float*)d_in[6];
  const float* w_kvI  = (const float*)d_in[7];
  const float* w_kvdw = (const float*)d_in[8];
  const float* w_proj = (const float*)d_in[9];
  float* out = (float*)d_out;

  float* ws   = (float*)d_ws;
  float* bufA = ws;                 // 64 MB: q_pre -> qdw (in place)
  float* bufB = ws + 16777216;      // 64 MB: k_pre -> kdw (in place)
  float* bufC = ws + 33554432;      // 64 MB: v_pre -> vdw bf16 (in place)
  float* sm   = ws + 50331648;      // small region at 192 MB
  float* mod  = sm;                 // 1024
  float* ssq  = sm + 1024;          // 1024 (q norms^2)
  float* ssk  = sm + 2048;          // 1024 (k norms^2)
  float* S    = sm + 3072;          // 32768 (Gram -> attn via smb)
  float* M    = sm + 3072 + 32768;  // 262144 (fused attn+proj matrix)

  // 1. mod + S-zeroing
  mod_kernel<<<dim3(4), dim3(256), 0, stream>>>(k_v, w_kR, w_kI, mod, S);

  // 2. q_pre -> A ; k_pre -> B ; v_pre -> C  (one launch, 3072 blocks)
  mgemm_qkv<<<dim3(128, 6, 4), dim3(256), 0, stream>>>(
      w_qR, w_kvI, x, mod, bufA, bufB, bufC);

  // 3. in-place dwconv x3: kdw(B)+ssk, qdw(A)+ssq, vdw(C, bf16)
  dw3_kernel<<<dim3(768, 4), dim3(256), 0, stream>>>(
      bufA, bufB, bufC, w_qdw, w_kvdw, ssq, ssk);

  // 4. Gram: S = qdw . kdw^T over pixels
  gram_kernel<<<dim3(16, 8, 4), dim3(256), 0, stream>>>(bufA, bufB, S);

  // 5. softmax + M = w_proj @ blockdiag(attn)
  smb_kernel<<<dim3(256, 4), dim3(256), 0, stream>>>(
      S, ssq, ssk, temp, w_proj, M);

  // 6. out = M[b] @ vdw[b] (bf16 vdw in C)
  mgemm_bx<<<dim3(128, 2, 4), dim3(256), 0, stream>>>(
      M, (const unsigned short*)bufC, out);
}